// Round 2
// baseline (926.490 us; speedup 1.0000x reference)
//
#include <hip/hip_runtime.h>
#include <hip/hip_bf16.h>
#include <math.h>

// ---------------------------------------------------------------------------
// GRAPH_VAE_V3: GCN-VAE encoder (2 branches x 3 GCN layers) + inner-product
// edge decoder.  fp32 throughout.  CSR built on-device each call (graph-safe).
// ---------------------------------------------------------------------------

__global__ void zero_int_k(int* __restrict__ p, int n) {
    int i = blockIdx.x * blockDim.x + threadIdx.x;
    if (i < n) p[i] = 0;
}

__global__ void count_dst_k(const int* __restrict__ ei, int* __restrict__ cnt, int E) {
    int e = blockIdx.x * blockDim.x + threadIdx.x;
    if (e < E) atomicAdd(&cnt[ei[E + e]], 1);
}

__global__ void compute_dis_k(const int* __restrict__ cnt, float* __restrict__ dis, int n) {
    int i = blockIdx.x * blockDim.x + threadIdx.x;
    if (i < n) dis[i] = rsqrtf((float)cnt[i] + 1.0f);
}

// single-block scan: row_ptr (exclusive -> row_ptr[i+1]=incl) and woff[i]=row_ptr[i]
__global__ void scan_rowptr_k(const int* __restrict__ cnt, int* __restrict__ row_ptr,
                              int* __restrict__ woff, int n) {
    __shared__ int smem[1024];
    __shared__ int carry;
    int tid = threadIdx.x;
    if (tid == 0) { carry = 0; row_ptr[0] = 0; }
    __syncthreads();
    for (int base = 0; base < n; base += 1024) {
        int i = base + tid;
        int v = (i < n) ? cnt[i] : 0;
        smem[tid] = v;
        __syncthreads();
        for (int off = 1; off < 1024; off <<= 1) {
            int add = (tid >= off) ? smem[tid - off] : 0;
            __syncthreads();
            smem[tid] += add;
            __syncthreads();
        }
        int incl = smem[tid] + carry;
        if (i < n) { row_ptr[i + 1] = incl; woff[i] = incl - v; }
        __syncthreads();
        if (tid == 0) carry += smem[1023];
        __syncthreads();
    }
}

__global__ void scatter_edges_k(const int* __restrict__ ei, const float* __restrict__ dis,
                                int* __restrict__ woff, int* __restrict__ src_sorted,
                                float* __restrict__ norm_sorted, int E) {
    int e = blockIdx.x * blockDim.x + threadIdx.x;
    if (e < E) {
        int s = ei[e];
        int d = ei[E + e];
        int pos = atomicAdd(&woff[d], 1);
        src_sorted[pos]  = s;
        norm_sorted[pos] = dis[s] * dis[d];
    }
}

// H[n x OUT] = A[n x K] @ W[K x OUT].  256 threads, each computes 4 rows x 4 cols.
template <int K, int OUT>
__global__ __launch_bounds__(256) void matmul_k(const float* __restrict__ A,
                                                const float* __restrict__ W,
                                                float* __restrict__ H, int n) {
    constexpr int TX = OUT / 4;   // threads along cols (16 or 32)
    constexpr int TY = 256 / TX;  // threads along rows (16 or 8)
    constexpr int TM = TY * 4;    // rows per block (64 or 32)
    __shared__ float w_lds[K * OUT];

    int tid = threadIdx.x;
    for (int idx = tid; idx < K * OUT / 4; idx += 256)
        ((float4*)w_lds)[idx] = ((const float4*)W)[idx];

    int tx = tid % TX;
    int ty = tid / TX;
    int row0 = blockIdx.x * TM;

    const float* Ar[4];
    bool val[4];
#pragma unroll
    for (int i = 0; i < 4; ++i) {
        int r = row0 + ty * 4 + i;
        val[i] = (r < n);
        Ar[i] = A + (size_t)(val[i] ? r : 0) * K;
    }

    float4 acc[4];
#pragma unroll
    for (int i = 0; i < 4; ++i) acc[i] = make_float4(0.f, 0.f, 0.f, 0.f);

    __syncthreads();

    for (int k = 0; k < K; k += 4) {
        float af[4][4];
#pragma unroll
        for (int i = 0; i < 4; ++i) {
            float4 a = val[i] ? *(const float4*)(Ar[i] + k) : make_float4(0.f, 0.f, 0.f, 0.f);
            af[i][0] = a.x; af[i][1] = a.y; af[i][2] = a.z; af[i][3] = a.w;
        }
#pragma unroll
        for (int j = 0; j < 4; ++j) {
            float4 wv = ((const float4*)w_lds)[(k + j) * TX + tx];
#pragma unroll
            for (int i = 0; i < 4; ++i) {
                acc[i].x += af[i][j] * wv.x;
                acc[i].y += af[i][j] * wv.y;
                acc[i].z += af[i][j] * wv.z;
                acc[i].w += af[i][j] * wv.w;
            }
        }
    }

#pragma unroll
    for (int i = 0; i < 4; ++i) {
        int r = row0 + ty * 4 + i;
        if (r < n) *(float4*)&H[(size_t)r * OUT + tx * 4] = acc[i];
    }
}

// CSR aggregation: out = relu( selfloop + sum_edges h[src]*norm + bias ) [,min 10]
// one wave per node, lane = channel (OUT=64) or 2 channels (OUT=128)
template <int OUT, int MODE>  // MODE 0: relu   1: relu + clamp(<=10)
__global__ void agg_k(const float* __restrict__ h, const float* __restrict__ dis,
                      const int* __restrict__ row_ptr, const int* __restrict__ srcs,
                      const float* __restrict__ norms, const float* __restrict__ bias,
                      float* __restrict__ out, int n) {
    int wid  = (int)((blockIdx.x * (size_t)blockDim.x + threadIdx.x) >> 6);
    int lane = threadIdx.x & 63;
    if (wid >= n) return;
    float di   = dis[wid];
    float self = di * di;
    int beg = row_ptr[wid], end = row_ptr[wid + 1];

    if (OUT == 64) {
        float acc = h[(size_t)wid * 64 + lane] * self;
        for (int e = beg; e < end; ++e) {
            int s = srcs[e];
            float nv = norms[e];
            acc = fmaf(h[(size_t)s * 64 + lane], nv, acc);
        }
        float r = acc + bias[lane];
        r = fmaxf(r, 0.f);
        if (MODE == 1) r = fminf(r, 10.f);
        out[(size_t)wid * 64 + lane] = r;
    } else {
        float acc0 = h[(size_t)wid * 128 + lane] * self;
        float acc1 = h[(size_t)wid * 128 + 64 + lane] * self;
        for (int e = beg; e < end; ++e) {
            int s = srcs[e];
            float nv = norms[e];
            acc0 = fmaf(h[(size_t)s * 128 + lane], nv, acc0);
            acc1 = fmaf(h[(size_t)s * 128 + 64 + lane], nv, acc1);
        }
        float r0 = acc0 + bias[lane];
        float r1 = acc1 + bias[lane + 64];
        r0 = fmaxf(r0, 0.f);
        r1 = fmaxf(r1, 0.f);
        if (MODE == 1) { r0 = fminf(r0, 10.f); r1 = fminf(r1, 10.f); }
        out[(size_t)wid * 128 + lane]      = r0;
        out[(size_t)wid * 128 + 64 + lane] = r1;
    }
}

// z = mu + eps * exp(logstd)   (vectorized over N*64/4)
__global__ void z_k(const float* __restrict__ mu, const float* __restrict__ ls,
                    const float* __restrict__ eps, float* __restrict__ z, int n4) {
    int i = blockIdx.x * blockDim.x + threadIdx.x;
    if (i < n4) {
        float4 m = ((const float4*)mu)[i];
        float4 l = ((const float4*)ls)[i];
        float4 e = ((const float4*)eps)[i];
        float4 r;
        r.x = m.x + e.x * expf(l.x);
        r.y = m.y + e.y * expf(l.y);
        r.z = m.z + e.z * expf(l.z);
        r.w = m.w + e.w * expf(l.w);
        ((float4*)z)[i] = r;
    }
}

// adj[e] = sigmoid( dot(z[src], z[dst]) ), one wave per edge, lane = channel
__global__ void decoder_k(const int* __restrict__ ei, const float* __restrict__ z,
                          float* __restrict__ adj, int E) {
    size_t gid = blockIdx.x * (size_t)blockDim.x + threadIdx.x;
    int e    = (int)(gid >> 6);
    int lane = threadIdx.x & 63;
    if (e >= E) return;
    int s = ei[e];
    int d = ei[E + e];
    float p = z[(size_t)s * 64 + lane] * z[(size_t)d * 64 + lane];
#pragma unroll
    for (int m = 32; m > 0; m >>= 1) p += __shfl_xor(p, m, 64);
    if (lane == 0) adj[e] = 1.f / (1.f + expf(-p));
}

extern "C" void kernel_launch(void* const* d_in, const int* in_sizes, int n_in,
                              void* d_out, int out_size, void* d_ws, size_t ws_size,
                              hipStream_t stream) {
    const float* x   = (const float*)d_in[0];
    const int*   ei  = (const int*)d_in[1];
    const float* eps = (const float*)d_in[2];
    const float* w_mu1 = (const float*)d_in[3];
    const float* b_mu1 = (const float*)d_in[4];
    const float* w_mu2 = (const float*)d_in[5];
    const float* b_mu2 = (const float*)d_in[6];
    const float* w_mu3 = (const float*)d_in[7];
    const float* b_mu3 = (const float*)d_in[8];
    const float* w_ls1 = (const float*)d_in[9];
    const float* b_ls1 = (const float*)d_in[10];
    const float* w_ls2 = (const float*)d_in[11];
    const float* b_ls2 = (const float*)d_in[12];
    const float* w_ls3 = (const float*)d_in[13];
    const float* b_ls3 = (const float*)d_in[14];

    const int N = in_sizes[0] / 128;
    const int E = in_sizes[1] / 2;
    const int LAT = 64;

    float* out = (float*)d_out;
    float* adj = out;              // [E]
    float* mu  = out + E;          // [N*64]
    float* ls  = out + E + (size_t)N * LAT;  // [N*64]

    // workspace layout (element offsets, padded to 256-elt multiples)
    float* ws = (float*)d_ws;
    const size_t P  = 50176;   // >= N, >= N+1
    const size_t EP = 600064;  // >= E
    float* dis         = ws;
    int*   cnt         = (int*)(ws + P);
    int*   row_ptr     = (int*)(ws + 2 * P);
    int*   woff        = (int*)(ws + 3 * P);
    int*   src_sorted  = (int*)(ws + 4 * P);
    float* norm_sorted = ws + 4 * P + EP;
    float* bufA        = ws + 4 * P + 2 * EP;           // N*128
    float* bufB        = bufA + (size_t)N * 128 + 256;  // N*128
    float* zbuf        = bufB + (size_t)N * 128 + 256;  // N*64

    // ---- CSR build ----
    zero_int_k<<<(N + 255) / 256, 256, 0, stream>>>(cnt, N);
    count_dst_k<<<(E + 255) / 256, 256, 0, stream>>>(ei, cnt, E);
    compute_dis_k<<<(N + 255) / 256, 256, 0, stream>>>(cnt, dis, N);
    scan_rowptr_k<<<1, 1024, 0, stream>>>(cnt, row_ptr, woff, N);
    scatter_edges_k<<<(E + 255) / 256, 256, 0, stream>>>(ei, dis, woff, src_sorted,
                                                         norm_sorted, E);

    const int aggBlocks64 = (int)(((size_t)N * 64 + 255) / 256);

    // ---- one encoder branch ----
    auto branch = [&](const float* w1, const float* b1, const float* w2, const float* b2,
                      const float* w3, const float* b3, float* final_out, bool clamp) {
        matmul_k<128, 64><<<(N + 63) / 64, 256, 0, stream>>>(x, w1, bufA, N);
        agg_k<64, 0><<<aggBlocks64, 256, 0, stream>>>(bufA, dis, row_ptr, src_sorted,
                                                      norm_sorted, b1, bufB, N);
        matmul_k<64, 128><<<(N + 31) / 32, 256, 0, stream>>>(bufB, w2, bufA, N);
        agg_k<128, 0><<<aggBlocks64, 256, 0, stream>>>(bufA, dis, row_ptr, src_sorted,
                                                       norm_sorted, b2, bufB, N);
        matmul_k<128, 64><<<(N + 63) / 64, 256, 0, stream>>>(bufB, w3, bufA, N);
        if (clamp)
            agg_k<64, 1><<<aggBlocks64, 256, 0, stream>>>(bufA, dis, row_ptr, src_sorted,
                                                          norm_sorted, b3, final_out, N);
        else
            agg_k<64, 0><<<aggBlocks64, 256, 0, stream>>>(bufA, dis, row_ptr, src_sorted,
                                                          norm_sorted, b3, final_out, N);
    };

    branch(w_mu1, b_mu1, w_mu2, b_mu2, w_mu3, b_mu3, mu, false);
    branch(w_ls1, b_ls1, w_ls2, b_ls2, w_ls3, b_ls3, ls, true);

    // ---- reparametrize + decode ----
    int n4 = N * LAT / 4;
    z_k<<<(n4 + 255) / 256, 256, 0, stream>>>(mu, ls, eps, zbuf, n4);
    decoder_k<<<(int)(((size_t)E * 64 + 255) / 256), 256, 0, stream>>>(ei, zbuf, adj, E);
}

// Round 5
// 672.266 us; speedup vs baseline: 1.3782x; 1.3782x over previous
//
#include <hip/hip_runtime.h>
#include <hip/hip_bf16.h>
#include <math.h>

// ---------------------------------------------------------------------------
// GRAPH_VAE_V3: GCN-VAE encoder (2 branches x 3 GCN layers) + inner-product
// edge decoder.  fp32 throughout.  CSR built on-device each call (graph-safe).
// R3: LDS-staged swizzled matmul, 16-lane/edge float4 decoder, shfl-scan.
// ---------------------------------------------------------------------------

__global__ void zero_int_k(int* __restrict__ p, int n) {
    int i = blockIdx.x * blockDim.x + threadIdx.x;
    if (i < n) p[i] = 0;
}

__global__ void count_dst_k(const int* __restrict__ ei, int* __restrict__ cnt, int E) {
    int e = blockIdx.x * blockDim.x + threadIdx.x;
    if (e < E) atomicAdd(&cnt[ei[E + e]], 1);
}

__global__ void compute_dis_k(const int* __restrict__ cnt, float* __restrict__ dis, int n) {
    int i = blockIdx.x * blockDim.x + threadIdx.x;
    if (i < n) dis[i] = rsqrtf((float)cnt[i] + 1.0f);
}

// wave-shuffle scan: row_ptr[i+1]=incl prefix, woff[i]=excl prefix
__global__ void scan_rowptr_k(const int* __restrict__ cnt, int* __restrict__ row_ptr,
                              int* __restrict__ woff, int n) {
    __shared__ int wsum[16];
    __shared__ int carry_s;
    int tid  = threadIdx.x;
    int lane = tid & 63;
    int wv   = tid >> 6;
    if (tid == 0) { carry_s = 0; row_ptr[0] = 0; }
    __syncthreads();
    for (int base = 0; base < n; base += 1024) {
        int i = base + tid;
        int v = (i < n) ? cnt[i] : 0;
        int x = v;
#pragma unroll
        for (int off = 1; off < 64; off <<= 1) {
            int t = __shfl_up(x, off, 64);
            if (lane >= off) x += t;
        }
        if (lane == 63) wsum[wv] = x;
        __syncthreads();
        if (wv == 0 && lane < 16) {
            int y = wsum[lane];
#pragma unroll
            for (int off = 1; off < 16; off <<= 1) {
                int t = __shfl_up(y, off, 64);
                if (lane >= off) y += t;
            }
            wsum[lane] = y;  // inclusive over wave sums
        }
        __syncthreads();
        int wbase = (wv == 0) ? 0 : wsum[wv - 1];
        int incl  = x + wbase + carry_s;
        if (i < n) { row_ptr[i + 1] = incl; woff[i] = incl - v; }
        __syncthreads();
        if (tid == 0) carry_s += wsum[15];
        __syncthreads();
    }
}

__global__ void scatter_edges_k(const int* __restrict__ ei, const float* __restrict__ dis,
                                int* __restrict__ woff, int* __restrict__ src_sorted,
                                float* __restrict__ norm_sorted, int E) {
    int e = blockIdx.x * blockDim.x + threadIdx.x;
    if (e < E) {
        int s = ei[e];
        int d = ei[E + e];
        int pos = atomicAdd(&woff[d], 1);
        src_sorted[pos]  = s;
        norm_sorted[pos] = dis[s] * dis[d];
    }
}

// H[n x OUT] = A[n x K] @ W[K x OUT].
// 256 threads; A-tile staged in LDS via coalesced float4 with XOR bank swizzle.
template <int K, int OUT>
__global__ __launch_bounds__(256) void matmul_k(const float* __restrict__ A,
                                                const float* __restrict__ W,
                                                float* __restrict__ H, int n) {
    constexpr int TX = OUT / 4;   // threads along cols (16 or 32)
    constexpr int TY = 256 / TX;  // threads along rows (16 or 8)
    constexpr int TM = TY * 4;    // rows per block (64 or 32)
    constexpr int K4 = K / 4;     // float4s per row (32 or 16)
    __shared__ float w_lds[K * OUT];
    __shared__ float a_lds[TM * K];

    int tid = threadIdx.x;
    // stage W (KxOUT contiguous)
    for (int idx = tid; idx < K * OUT / 4; idx += 256)
        ((float4*)w_lds)[idx] = ((const float4*)W)[idx];

    // stage A-tile: rows row0..row0+TM-1 are contiguous in global memory.
    int row0 = blockIdx.x * TM;
    const float4* Ag = (const float4*)(A + (size_t)row0 * K);
    for (int f4 = tid; f4 < TM * K4; f4 += 256) {
        int row  = f4 / K4;
        int col4 = f4 % K4;
        float4 v = (row0 + row < n) ? Ag[f4] : make_float4(0.f, 0.f, 0.f, 0.f);
        // XOR swizzle breaks stride-K bank aliasing (K%32==0)
        *(float4*)&a_lds[row * K + ((col4 ^ (row & 15)) << 2)] = v;
    }
    __syncthreads();

    int tx = tid % TX;
    int ty = tid / TX;

    int abase[4], axr[4];
#pragma unroll
    for (int i = 0; i < 4; ++i) {
        int r = ty * 4 + i;
        abase[i] = r * K;
        axr[i]   = r & 15;
    }

    float4 acc[4];
#pragma unroll
    for (int i = 0; i < 4; ++i) acc[i] = make_float4(0.f, 0.f, 0.f, 0.f);

#pragma unroll 4
    for (int k = 0; k < K; k += 4) {
        int k4 = k >> 2;
        float af[4][4];
#pragma unroll
        for (int i = 0; i < 4; ++i) {
            float4 a = *(const float4*)&a_lds[abase[i] + ((k4 ^ axr[i]) << 2)];
            af[i][0] = a.x; af[i][1] = a.y; af[i][2] = a.z; af[i][3] = a.w;
        }
#pragma unroll
        for (int j = 0; j < 4; ++j) {
            float4 wv = ((const float4*)w_lds)[(k + j) * TX + tx];
#pragma unroll
            for (int i = 0; i < 4; ++i) {
                acc[i].x += af[i][j] * wv.x;
                acc[i].y += af[i][j] * wv.y;
                acc[i].z += af[i][j] * wv.z;
                acc[i].w += af[i][j] * wv.w;
            }
        }
    }

#pragma unroll
    for (int i = 0; i < 4; ++i) {
        int r = row0 + ty * 4 + i;
        if (r < n) *(float4*)&H[(size_t)r * OUT + tx * 4] = acc[i];
    }
}

// CSR aggregation: out = relu( selfloop + sum_edges h[src]*norm + bias ) [,min 10]
template <int OUT, int MODE>  // MODE 0: relu   1: relu + clamp(<=10)
__global__ void agg_k(const float* __restrict__ h, const float* __restrict__ dis,
                      const int* __restrict__ row_ptr, const int* __restrict__ srcs,
                      const float* __restrict__ norms, const float* __restrict__ bias,
                      float* __restrict__ out, int n) {
    int wid  = (int)((blockIdx.x * (size_t)blockDim.x + threadIdx.x) >> 6);
    int lane = threadIdx.x & 63;
    if (wid >= n) return;
    float di   = dis[wid];
    float self = di * di;
    int beg = row_ptr[wid], end = row_ptr[wid + 1];

    if (OUT == 64) {
        float acc = h[(size_t)wid * 64 + lane] * self;
        for (int e = beg; e < end; ++e) {
            int s = srcs[e];
            float nv = norms[e];
            acc = fmaf(h[(size_t)s * 64 + lane], nv, acc);
        }
        float r = acc + bias[lane];
        r = fmaxf(r, 0.f);
        if (MODE == 1) r = fminf(r, 10.f);
        out[(size_t)wid * 64 + lane] = r;
    } else {
        float acc0 = h[(size_t)wid * 128 + lane] * self;
        float acc1 = h[(size_t)wid * 128 + 64 + lane] * self;
        for (int e = beg; e < end; ++e) {
            int s = srcs[e];
            float nv = norms[e];
            acc0 = fmaf(h[(size_t)s * 128 + lane], nv, acc0);
            acc1 = fmaf(h[(size_t)s * 128 + 64 + lane], nv, acc1);
        }
        float r0 = acc0 + bias[lane];
        float r1 = acc1 + bias[lane + 64];
        r0 = fmaxf(r0, 0.f);
        r1 = fmaxf(r1, 0.f);
        if (MODE == 1) { r0 = fminf(r0, 10.f); r1 = fminf(r1, 10.f); }
        out[(size_t)wid * 128 + lane]      = r0;
        out[(size_t)wid * 128 + 64 + lane] = r1;
    }
}

// z = mu + eps * exp(logstd)
__global__ void z_k(const float* __restrict__ mu, const float* __restrict__ ls,
                    const float* __restrict__ eps, float* __restrict__ z, int n4) {
    int i = blockIdx.x * blockDim.x + threadIdx.x;
    if (i < n4) {
        float4 m = ((const float4*)mu)[i];
        float4 l = ((const float4*)ls)[i];
        float4 e = ((const float4*)eps)[i];
        float4 r;
        r.x = m.x + e.x * expf(l.x);
        r.y = m.y + e.y * expf(l.y);
        r.z = m.z + e.z * expf(l.z);
        r.w = m.w + e.w * expf(l.w);
        ((float4*)z)[i] = r;
    }
}

// adj[e] = sigmoid( dot(z[src], z[dst]) ): 16 lanes per edge, float4 per lane
__global__ void decoder_k(const int* __restrict__ ei, const float* __restrict__ z,
                          float* __restrict__ adj, int E) {
    int t = blockIdx.x * 256 + threadIdx.x;
    int e = t >> 4;
    int q = threadIdx.x & 15;
    if (e >= E) return;
    int s = ei[e];
    int d = ei[E + e];
    const float4* z4 = (const float4*)z;
    float4 a = z4[(size_t)s * 16 + q];
    float4 b = z4[(size_t)d * 16 + q];
    float p = a.x * b.x + a.y * b.y + a.z * b.z + a.w * b.w;
    p += __shfl_xor(p, 8);
    p += __shfl_xor(p, 4);
    p += __shfl_xor(p, 2);
    p += __shfl_xor(p, 1);
    if (q == 0) adj[e] = 1.f / (1.f + expf(-p));
}

extern "C" void kernel_launch(void* const* d_in, const int* in_sizes, int n_in,
                              void* d_out, int out_size, void* d_ws, size_t ws_size,
                              hipStream_t stream) {
    const float* x   = (const float*)d_in[0];
    const int*   ei  = (const int*)d_in[1];
    const float* eps = (const float*)d_in[2];
    const float* w_mu1 = (const float*)d_in[3];
    const float* b_mu1 = (const float*)d_in[4];
    const float* w_mu2 = (const float*)d_in[5];
    const float* b_mu2 = (const float*)d_in[6];
    const float* w_mu3 = (const float*)d_in[7];
    const float* b_mu3 = (const float*)d_in[8];
    const float* w_ls1 = (const float*)d_in[9];
    const float* b_ls1 = (const float*)d_in[10];
    const float* w_ls2 = (const float*)d_in[11];
    const float* b_ls2 = (const float*)d_in[12];
    const float* w_ls3 = (const float*)d_in[13];
    const float* b_ls3 = (const float*)d_in[14];

    const int N = in_sizes[0] / 128;
    const int E = in_sizes[1] / 2;
    const int LAT = 64;

    float* out = (float*)d_out;
    float* adj = out;              // [E]
    float* mu  = out + E;          // [N*64]
    float* ls  = out + E + (size_t)N * LAT;  // [N*64]

    float* ws = (float*)d_ws;
    const size_t P  = 50176;   // >= N, >= N+1
    const size_t EP = 600064;  // >= E
    float* dis         = ws;
    int*   cnt         = (int*)(ws + P);
    int*   row_ptr     = (int*)(ws + 2 * P);
    int*   woff        = (int*)(ws + 3 * P);
    int*   src_sorted  = (int*)(ws + 4 * P);
    float* norm_sorted = ws + 4 * P + EP;
    float* bufA        = ws + 4 * P + 2 * EP;           // N*128
    float* bufB        = bufA + (size_t)N * 128 + 256;  // N*128
    float* zbuf        = bufB + (size_t)N * 128 + 256;  // N*64

    // ---- CSR build ----
    zero_int_k<<<(N + 255) / 256, 256, 0, stream>>>(cnt, N);
    count_dst_k<<<(E + 255) / 256, 256, 0, stream>>>(ei, cnt, E);
    compute_dis_k<<<(N + 255) / 256, 256, 0, stream>>>(cnt, dis, N);
    scan_rowptr_k<<<1, 1024, 0, stream>>>(cnt, row_ptr, woff, N);
    scatter_edges_k<<<(E + 255) / 256, 256, 0, stream>>>(ei, dis, woff, src_sorted,
                                                         norm_sorted, E);

    const int aggBlocks64 = (int)(((size_t)N * 64 + 255) / 256);

    auto branch = [&](const float* w1, const float* b1, const float* w2, const float* b2,
                      const float* w3, const float* b3, float* final_out, bool clamp) {
        matmul_k<128, 64><<<(N + 63) / 64, 256, 0, stream>>>(x, w1, bufA, N);
        agg_k<64, 0><<<aggBlocks64, 256, 0, stream>>>(bufA, dis, row_ptr, src_sorted,
                                                      norm_sorted, b1, bufB, N);
        matmul_k<64, 128><<<(N + 31) / 32, 256, 0, stream>>>(bufB, w2, bufA, N);
        agg_k<128, 0><<<aggBlocks64, 256, 0, stream>>>(bufA, dis, row_ptr, src_sorted,
                                                       norm_sorted, b2, bufB, N);
        matmul_k<128, 64><<<(N + 63) / 64, 256, 0, stream>>>(bufB, w3, bufA, N);
        if (clamp)
            agg_k<64, 1><<<aggBlocks64, 256, 0, stream>>>(bufA, dis, row_ptr, src_sorted,
                                                          norm_sorted, b3, final_out, N);
        else
            agg_k<64, 0><<<aggBlocks64, 256, 0, stream>>>(bufA, dis, row_ptr, src_sorted,
                                                          norm_sorted, b3, final_out, N);
    };

    branch(w_mu1, b_mu1, w_mu2, b_mu2, w_mu3, b_mu3, mu, false);
    branch(w_ls1, b_ls1, w_ls2, b_ls2, w_ls3, b_ls3, ls, true);

    int n4 = N * LAT / 4;
    z_k<<<(n4 + 255) / 256, 256, 0, stream>>>(mu, ls, eps, zbuf, n4);
    decoder_k<<<(int)(((size_t)E * 16 + 255) / 256), 256, 0, stream>>>(ei, zbuf, adj, E);
}

// Round 6
// 461.382 us; speedup vs baseline: 2.0081x; 1.4571x over previous
//
#include <hip/hip_runtime.h>
#include <hip/hip_bf16.h>
#include <math.h>

// ---------------------------------------------------------------------------
// GRAPH_VAE_V3: GCN-VAE encoder + inner-product decoder.  fp32.
// R5: A(hW)=(Ah)W reorder (all aggs at dim 64/branch), dual-branch fused
// aggregation with interleaved [mu64|ls64] rows, shfl edge-chunk broadcast,
// matmul bias+relu epilogue, z fused into final agg.
// ---------------------------------------------------------------------------

__global__ void zero_int_k(int* __restrict__ p, int n) {
    int i = blockIdx.x * blockDim.x + threadIdx.x;
    if (i < n) p[i] = 0;
}

__global__ void count_dst_k(const int* __restrict__ ei, int* __restrict__ cnt, int E) {
    int e = blockIdx.x * blockDim.x + threadIdx.x;
    if (e < E) atomicAdd(&cnt[ei[E + e]], 1);
}

__global__ void compute_dis_k(const int* __restrict__ cnt, float* __restrict__ dis, int n) {
    int i = blockIdx.x * blockDim.x + threadIdx.x;
    if (i < n) dis[i] = rsqrtf((float)cnt[i] + 1.0f);
}

// wave-shuffle scan: row_ptr[i+1]=incl prefix, woff[i]=excl prefix
__global__ void scan_rowptr_k(const int* __restrict__ cnt, int* __restrict__ row_ptr,
                              int* __restrict__ woff, int n) {
    __shared__ int wsum[16];
    __shared__ int carry_s;
    int tid  = threadIdx.x;
    int lane = tid & 63;
    int wv   = tid >> 6;
    if (tid == 0) { carry_s = 0; row_ptr[0] = 0; }
    __syncthreads();
    for (int base = 0; base < n; base += 1024) {
        int i = base + tid;
        int v = (i < n) ? cnt[i] : 0;
        int x = v;
#pragma unroll
        for (int off = 1; off < 64; off <<= 1) {
            int t = __shfl_up(x, off, 64);
            if (lane >= off) x += t;
        }
        if (lane == 63) wsum[wv] = x;
        __syncthreads();
        if (wv == 0 && lane < 16) {
            int y = wsum[lane];
#pragma unroll
            for (int off = 1; off < 16; off <<= 1) {
                int t = __shfl_up(y, off, 64);
                if (lane >= off) y += t;
            }
            wsum[lane] = y;
        }
        __syncthreads();
        int wbase = (wv == 0) ? 0 : wsum[wv - 1];
        int incl  = x + wbase + carry_s;
        if (i < n) { row_ptr[i + 1] = incl; woff[i] = incl - v; }
        __syncthreads();
        if (tid == 0) carry_s += wsum[15];
        __syncthreads();
    }
}

__global__ void scatter_edges_k(const int* __restrict__ ei, const float* __restrict__ dis,
                                int* __restrict__ woff, int* __restrict__ src_sorted,
                                float* __restrict__ norm_sorted, int E) {
    int e = blockIdx.x * blockDim.x + threadIdx.x;
    if (e < E) {
        int s = ei[e];
        int d = ei[E + e];
        int pos = atomicAdd(&woff[d], 1);
        src_sorted[pos]  = s;
        norm_sorted[pos] = dis[s] * dis[d];
    }
}

// H[r*ldh+offh .. +OUT] = A[r*lda+offa .. +K] @ W[K x OUT]  (+bias, relu if EPI=1)
template <int K, int OUT, int EPI>
__global__ __launch_bounds__(256) void matmul_k(const float* __restrict__ A, int lda, int offa,
                                                const float* __restrict__ W,
                                                const float* __restrict__ bias,
                                                float* __restrict__ H, int ldh, int offh,
                                                int n) {
    constexpr int TX = OUT / 4;
    constexpr int TY = 256 / TX;
    constexpr int TM = TY * 4;
    constexpr int K4 = K / 4;
    __shared__ float w_lds[K * OUT];
    __shared__ float a_lds[TM * K];

    int tid = threadIdx.x;
    for (int idx = tid; idx < K * OUT / 4; idx += 256)
        ((float4*)w_lds)[idx] = ((const float4*)W)[idx];

    int row0 = blockIdx.x * TM;
    for (int f4 = tid; f4 < TM * K4; f4 += 256) {
        int row  = f4 / K4;
        int col4 = f4 % K4;
        float4 v = make_float4(0.f, 0.f, 0.f, 0.f);
        if (row0 + row < n)
            v = *(const float4*)&A[(size_t)(row0 + row) * lda + offa + (col4 << 2)];
        *(float4*)&a_lds[row * K + ((col4 ^ (row & 15)) << 2)] = v;  // XOR bank swizzle
    }
    __syncthreads();

    int tx = tid % TX;
    int ty = tid / TX;

    int abase[4], axr[4];
#pragma unroll
    for (int i = 0; i < 4; ++i) {
        int r = ty * 4 + i;
        abase[i] = r * K;
        axr[i]   = r & 15;
    }

    float4 acc[4];
#pragma unroll
    for (int i = 0; i < 4; ++i) acc[i] = make_float4(0.f, 0.f, 0.f, 0.f);

#pragma unroll 4
    for (int k = 0; k < K; k += 4) {
        int k4 = k >> 2;
        float af[4][4];
#pragma unroll
        for (int i = 0; i < 4; ++i) {
            float4 a = *(const float4*)&a_lds[abase[i] + ((k4 ^ axr[i]) << 2)];
            af[i][0] = a.x; af[i][1] = a.y; af[i][2] = a.z; af[i][3] = a.w;
        }
#pragma unroll
        for (int j = 0; j < 4; ++j) {
            float4 wv = ((const float4*)w_lds)[(k + j) * TX + tx];
#pragma unroll
            for (int i = 0; i < 4; ++i) {
                acc[i].x += af[i][j] * wv.x;
                acc[i].y += af[i][j] * wv.y;
                acc[i].z += af[i][j] * wv.z;
                acc[i].w += af[i][j] * wv.w;
            }
        }
    }

#pragma unroll
    for (int i = 0; i < 4; ++i) {
        int r = row0 + ty * 4 + i;
        if (r < n) {
            float4 o = acc[i];
            if (EPI == 1) {
                float4 b = ((const float4*)bias)[tx];
                o.x = fmaxf(o.x + b.x, 0.f);
                o.y = fmaxf(o.y + b.y, 0.f);
                o.z = fmaxf(o.z + b.z, 0.f);
                o.w = fmaxf(o.w + b.w, 0.f);
            }
            *(float4*)&H[(size_t)r * ldh + offh + tx * 4] = o;
        }
    }
}

// Dual-branch CSR aggregation over interleaved rows h[node] = [mu 64 | ls 64].
// One wave per node; edge indices chunk-loaded coalesced then shfl-broadcast.
// MODE 0: raw agg -> interleaved oI            (pre-matmul, layer 2)
// MODE 1: relu(agg+b) -> interleaved oI        (layer 1)
// MODE 2: relu(+clamp ls) -> mu/ls arrays, z = mu + eps*exp(ls)  (layer 3)
template <int MODE>
__global__ void agg2_k(const float* __restrict__ h, const float* __restrict__ dis,
                       const int* __restrict__ row_ptr, const int* __restrict__ srcs,
                       const float* __restrict__ norms,
                       const float* __restrict__ bM, const float* __restrict__ bL,
                       const float* __restrict__ eps,
                       float* __restrict__ oI,
                       float* __restrict__ oM, float* __restrict__ oL,
                       float* __restrict__ z, int n) {
    int wid  = (int)((blockIdx.x * (size_t)blockDim.x + threadIdx.x) >> 6);
    int lane = threadIdx.x & 63;
    if (wid >= n) return;
    float di = dis[wid], self = di * di;
    int beg = row_ptr[wid], end = row_ptr[wid + 1];
    size_t rb = (size_t)wid * 128;
    float accM = h[rb + lane] * self;
    float accL = h[rb + 64 + lane] * self;

    for (int cb = beg; cb < end; cb += 64) {
        int m = end - cb;
        if (m > 64) m = 64;
        int sv = 0; float nv = 0.f;
        if (lane < m) { sv = srcs[cb + lane]; nv = norms[cb + lane]; }
        int j = 0;
        for (; j + 2 <= m; j += 2) {
            int   s0 = __shfl(sv, j, 64),     s1 = __shfl(sv, j + 1, 64);
            float w0 = __shfl(nv, j, 64),     w1 = __shfl(nv, j + 1, 64);
            size_t r0 = (size_t)s0 * 128, r1 = (size_t)s1 * 128;
            float m0 = h[r0 + lane], l0 = h[r0 + 64 + lane];
            float m1 = h[r1 + lane], l1 = h[r1 + 64 + lane];
            accM = fmaf(m0, w0, accM); accL = fmaf(l0, w0, accL);
            accM = fmaf(m1, w1, accM); accL = fmaf(l1, w1, accL);
        }
        if (j < m) {
            int s0 = __shfl(sv, j, 64);
            float w0 = __shfl(nv, j, 64);
            size_t r0 = (size_t)s0 * 128;
            accM = fmaf(h[r0 + lane], w0, accM);
            accL = fmaf(h[r0 + 64 + lane], w0, accL);
        }
    }

    if (MODE == 0) {
        oI[rb + lane]      = accM;
        oI[rb + 64 + lane] = accL;
    } else if (MODE == 1) {
        oI[rb + lane]      = fmaxf(accM + bM[lane], 0.f);
        oI[rb + 64 + lane] = fmaxf(accL + bL[lane], 0.f);
    } else {
        size_t ob = (size_t)wid * 64 + lane;
        float muv = fmaxf(accM + bM[lane], 0.f);
        float lsv = fminf(fmaxf(accL + bL[lane], 0.f), 10.f);
        oM[ob] = muv;
        oL[ob] = lsv;
        z[ob]  = fmaf(eps[ob], expf(lsv), muv);
    }
}

// adj[e] = sigmoid( dot(z[src], z[dst]) ): 16 lanes per edge, float4 per lane
__global__ void decoder_k(const int* __restrict__ ei, const float* __restrict__ z,
                          float* __restrict__ adj, int E) {
    int t = blockIdx.x * 256 + threadIdx.x;
    int e = t >> 4;
    int q = threadIdx.x & 15;
    if (e >= E) return;
    int s = ei[e];
    int d = ei[E + e];
    const float4* z4 = (const float4*)z;
    float4 a = z4[(size_t)s * 16 + q];
    float4 b = z4[(size_t)d * 16 + q];
    float p = a.x * b.x + a.y * b.y + a.z * b.z + a.w * b.w;
    p += __shfl_xor(p, 8);
    p += __shfl_xor(p, 4);
    p += __shfl_xor(p, 2);
    p += __shfl_xor(p, 1);
    if (q == 0) adj[e] = 1.f / (1.f + expf(-p));
}

extern "C" void kernel_launch(void* const* d_in, const int* in_sizes, int n_in,
                              void* d_out, int out_size, void* d_ws, size_t ws_size,
                              hipStream_t stream) {
    const float* x   = (const float*)d_in[0];
    const int*   ei  = (const int*)d_in[1];
    const float* eps = (const float*)d_in[2];
    const float* w_mu1 = (const float*)d_in[3];
    const float* b_mu1 = (const float*)d_in[4];
    const float* w_mu2 = (const float*)d_in[5];
    const float* b_mu2 = (const float*)d_in[6];
    const float* w_mu3 = (const float*)d_in[7];
    const float* b_mu3 = (const float*)d_in[8];
    const float* w_ls1 = (const float*)d_in[9];
    const float* b_ls1 = (const float*)d_in[10];
    const float* w_ls2 = (const float*)d_in[11];
    const float* b_ls2 = (const float*)d_in[12];
    const float* w_ls3 = (const float*)d_in[13];
    const float* b_ls3 = (const float*)d_in[14];

    const int N = in_sizes[0] / 128;
    const int E = in_sizes[1] / 2;
    const size_t NB = (size_t)N * 128;  // interleaved node-feature buffer size

    float* out = (float*)d_out;
    float* adj = out;                        // [E]
    float* mu  = out + E;                    // [N*64]
    float* ls  = out + E + (size_t)N * 64;   // [N*64]
    float* M   = out + E;                    // mu|ls region doubles as N*128 scratch

    // workspace: R1 (N*128) | R3 (N*128) | CSR
    float* ws = (float*)d_ws;
    const size_t P  = 50176;   // >= N+1
    const size_t EP = 600064;  // >= E
    float* R1 = ws;
    float* R3 = ws + NB;
    float* c0 = ws + 2 * NB;
    float* dis         = c0;
    int*   cnt         = (int*)(c0 + P);
    int*   row_ptr     = (int*)(c0 + 2 * P);
    int*   woff        = (int*)(c0 + 3 * P);
    int*   src_sorted  = (int*)(c0 + 4 * P);
    float* norm_sorted = c0 + 4 * P + EP;

    // ---- CSR build ----
    zero_int_k<<<(N + 255) / 256, 256, 0, stream>>>(cnt, N);
    count_dst_k<<<(E + 255) / 256, 256, 0, stream>>>(ei, cnt, E);
    compute_dis_k<<<(N + 255) / 256, 256, 0, stream>>>(cnt, dis, N);
    scan_rowptr_k<<<1, 1024, 0, stream>>>(cnt, row_ptr, woff, N);
    scatter_edges_k<<<(E + 255) / 256, 256, 0, stream>>>(ei, dis, woff, src_sorted,
                                                         norm_sorted, E);

    const int aggBlocks = (int)(((size_t)N * 64 + 255) / 256);

    // ---- layer 1: t1 = x@W1 (both branches into R1 interleaved); h1 = relu(A t1 + b) -> M
    matmul_k<128, 64, 0><<<(N + 63) / 64, 256, 0, stream>>>(x, 128, 0, w_mu1, nullptr,
                                                            R1, 128, 0, N);
    matmul_k<128, 64, 0><<<(N + 63) / 64, 256, 0, stream>>>(x, 128, 0, w_ls1, nullptr,
                                                            R1, 128, 64, N);
    agg2_k<1><<<aggBlocks, 256, 0, stream>>>(R1, dis, row_ptr, src_sorted, norm_sorted,
                                             b_mu1, b_ls1, nullptr, M, nullptr, nullptr,
                                             nullptr, N);

    // ---- layer 2 (reordered): a2 = A h1 -> R1;  h2 = relu(a2@W2 + b2)
    agg2_k<0><<<aggBlocks, 256, 0, stream>>>(M, dis, row_ptr, src_sorted, norm_sorted,
                                             nullptr, nullptr, nullptr, R1, nullptr,
                                             nullptr, nullptr, N);
    matmul_k<64, 128, 1><<<(N + 31) / 32, 256, 0, stream>>>(R1, 128, 0, w_mu2, b_mu2,
                                                            M, 128, 0, N);   // h2_mu
    matmul_k<64, 128, 1><<<(N + 31) / 32, 256, 0, stream>>>(R1, 128, 64, w_ls2, b_ls2,
                                                            R3, 128, 0, N);  // h2_ls

    // ---- layer 3: m3 = h2@W3 (interleaved into R1); final agg + z
    matmul_k<128, 64, 0><<<(N + 63) / 64, 256, 0, stream>>>(M, 128, 0, w_mu3, nullptr,
                                                            R1, 128, 0, N);
    matmul_k<128, 64, 0><<<(N + 63) / 64, 256, 0, stream>>>(R3, 128, 0, w_ls3, nullptr,
                                                            R1, 128, 64, N);
    agg2_k<2><<<aggBlocks, 256, 0, stream>>>(R1, dis, row_ptr, src_sorted, norm_sorted,
                                             b_mu3, b_ls3, eps, nullptr, mu, ls, R3, N);

    // ---- decode ----
    decoder_k<<<(int)(((size_t)E * 16 + 255) / 256), 256, 0, stream>>>(ei, R3, adj, E);
}

// Round 7
// 389.955 us; speedup vs baseline: 2.3759x; 1.1832x over previous
//
#include <hip/hip_runtime.h>
#include <hip/hip_bf16.h>
#include <math.h>

// ---------------------------------------------------------------------------
// GRAPH_VAE_V3: GCN-VAE encoder + inner-product decoder.  fp32.
// R7: dual-edge float4 gather agg (0.5 load-instr/edge), parallel 3-phase
// scan, branch-pair fused matmul launches (gridDim.y=2).
// ---------------------------------------------------------------------------

__global__ void zero_int_k(int* __restrict__ p, int n) {
    int i = blockIdx.x * blockDim.x + threadIdx.x;
    if (i < n) p[i] = 0;
}

__global__ void count_dst_k(const int* __restrict__ ei, int* __restrict__ cnt, int E) {
    int e = blockIdx.x * blockDim.x + threadIdx.x;
    if (e < E) atomicAdd(&cnt[ei[E + e]], 1);
}

__global__ void compute_dis_k(const int* __restrict__ cnt, float* __restrict__ dis, int n) {
    int i = blockIdx.x * blockDim.x + threadIdx.x;
    if (i < n) dis[i] = rsqrtf((float)cnt[i] + 1.0f);
}

// ---- 3-phase parallel scan ----
// phase 1: per-block (1024 thr) local inclusive scan -> row_ptr[i+1], block sums
__global__ void scan1_k(const int* __restrict__ cnt, int* __restrict__ row_ptr,
                        int* __restrict__ bsum, int n) {
    __shared__ int wsum[16];
    int tid = threadIdx.x, lane = tid & 63, wv = tid >> 6;
    int i = blockIdx.x * 1024 + tid;
    int v = (i < n) ? cnt[i] : 0;
    int x = v;
#pragma unroll
    for (int off = 1; off < 64; off <<= 1) {
        int t = __shfl_up(x, off, 64);
        if (lane >= off) x += t;
    }
    if (lane == 63) wsum[wv] = x;
    __syncthreads();
    if (wv == 0 && lane < 16) {
        int y = wsum[lane];
#pragma unroll
        for (int off = 1; off < 16; off <<= 1) {
            int t = __shfl_up(y, off, 64);
            if (lane >= off) y += t;
        }
        wsum[lane] = y;
    }
    __syncthreads();
    int incl = x + ((wv == 0) ? 0 : wsum[wv - 1]);
    if (i < n) row_ptr[i + 1] = incl;
    if (tid == 1023) bsum[blockIdx.x] = incl;
}

// phase 2: exclusive scan of block sums (nb <= 64) in one wave
__global__ void scan2_k(int* __restrict__ bsum, int nb) {
    int lane = threadIdx.x;
    int v = (lane < nb) ? bsum[lane] : 0;
    int x = v;
#pragma unroll
    for (int off = 1; off < 64; off <<= 1) {
        int t = __shfl_up(x, off, 64);
        if (lane >= off) x += t;
    }
    if (lane < nb) bsum[lane] = x - v;
}

// phase 3: add block offsets; emit woff (exclusive) and row_ptr[0]
__global__ void scan3_k(const int* __restrict__ cnt, int* __restrict__ row_ptr,
                        const int* __restrict__ bsum, int* __restrict__ woff, int n) {
    int i = blockIdx.x * 1024 + threadIdx.x;
    if (i == 0) row_ptr[0] = 0;
    if (i < n) {
        int r = row_ptr[i + 1] + bsum[blockIdx.x];
        row_ptr[i + 1] = r;
        woff[i] = r - cnt[i];
    }
}

__global__ void scatter_edges_k(const int* __restrict__ ei, const float* __restrict__ dis,
                                int* __restrict__ woff, int* __restrict__ src_sorted,
                                float* __restrict__ norm_sorted, int E) {
    int e = blockIdx.x * blockDim.x + threadIdx.x;
    if (e < E) {
        int s = ei[e];
        int d = ei[E + e];
        int pos = atomicAdd(&woff[d], 1);
        src_sorted[pos]  = s;
        norm_sorted[pos] = dis[s] * dis[d];
    }
}

// Branch-pair matmul: blockIdx.y = branch b. H_b[r*ldh+offh_b ..] =
// A_b[r*lda+offa_b ..] @ W_b  (+bias,relu if EPI).
template <int K, int OUT, int EPI>
__global__ __launch_bounds__(256) void matmul2_k(
        const float* __restrict__ AA, const float* __restrict__ AB, int lda,
        int offaA, int offaB,
        const float* __restrict__ WA, const float* __restrict__ WB,
        const float* __restrict__ bA, const float* __restrict__ bB,
        float* __restrict__ HA, float* __restrict__ HB, int ldh,
        int offhA, int offhB, int n) {
    constexpr int TX = OUT / 4;
    constexpr int TY = 256 / TX;
    constexpr int TM = TY * 4;
    constexpr int K4 = K / 4;
    __shared__ float w_lds[K * OUT];
    __shared__ float a_lds[TM * K];

    int by = blockIdx.y;
    const float* A  = by ? AB : AA;
    const float* W  = by ? WB : WA;
    const float* bi = by ? bB : bA;
    float*       H  = by ? HB : HA;
    int offa = by ? offaB : offaA;
    int offh = by ? offhB : offhA;

    int tid = threadIdx.x;
    for (int idx = tid; idx < K * OUT / 4; idx += 256)
        ((float4*)w_lds)[idx] = ((const float4*)W)[idx];

    int row0 = blockIdx.x * TM;
    for (int f4 = tid; f4 < TM * K4; f4 += 256) {
        int row  = f4 / K4;
        int col4 = f4 % K4;
        float4 v = make_float4(0.f, 0.f, 0.f, 0.f);
        if (row0 + row < n)
            v = *(const float4*)&A[(size_t)(row0 + row) * lda + offa + (col4 << 2)];
        *(float4*)&a_lds[row * K + ((col4 ^ (row & 15)) << 2)] = v;  // XOR bank swizzle
    }
    __syncthreads();

    int tx = tid % TX;
    int ty = tid / TX;

    int abase[4], axr[4];
#pragma unroll
    for (int i = 0; i < 4; ++i) {
        int r = ty * 4 + i;
        abase[i] = r * K;
        axr[i]   = r & 15;
    }

    float4 acc[4];
#pragma unroll
    for (int i = 0; i < 4; ++i) acc[i] = make_float4(0.f, 0.f, 0.f, 0.f);

#pragma unroll 4
    for (int k = 0; k < K; k += 4) {
        int k4 = k >> 2;
        float af[4][4];
#pragma unroll
        for (int i = 0; i < 4; ++i) {
            float4 a = *(const float4*)&a_lds[abase[i] + ((k4 ^ axr[i]) << 2)];
            af[i][0] = a.x; af[i][1] = a.y; af[i][2] = a.z; af[i][3] = a.w;
        }
#pragma unroll
        for (int j = 0; j < 4; ++j) {
            float4 wv = ((const float4*)w_lds)[(k + j) * TX + tx];
#pragma unroll
            for (int i = 0; i < 4; ++i) {
                acc[i].x += af[i][j] * wv.x;
                acc[i].y += af[i][j] * wv.y;
                acc[i].z += af[i][j] * wv.z;
                acc[i].w += af[i][j] * wv.w;
            }
        }
    }

#pragma unroll
    for (int i = 0; i < 4; ++i) {
        int r = row0 + ty * 4 + i;
        if (r < n) {
            float4 o = acc[i];
            if (EPI == 1) {
                float4 b = ((const float4*)bi)[tx];
                o.x = fmaxf(o.x + b.x, 0.f);
                o.y = fmaxf(o.y + b.y, 0.f);
                o.z = fmaxf(o.z + b.z, 0.f);
                o.w = fmaxf(o.w + b.w, 0.f);
            }
            *(float4*)&H[(size_t)r * ldh + offh + tx * 4] = o;
        }
    }
}

// Dual-branch CSR aggregation, dual-edge float4 gather.
// Lane split: half = lane>>5 handles edge (j+half) of each pair;
// q = lane&31 owns channels 4q..4q+3 of the interleaved [mu64|ls64] row.
// One dwordx4 load instruction gathers TWO full 512B rows per pair.
// MODE 0: raw agg -> oI;  1: relu(agg+b) -> oI;
// MODE 2: mu=relu(+b), ls=clamp(relu(+b)), z=mu+eps*exp(ls) -> oM,oL,z
template <int MODE>
__global__ void agg2_k(const float* __restrict__ h, const float* __restrict__ dis,
                       const int* __restrict__ row_ptr, const int* __restrict__ srcs,
                       const float* __restrict__ norms,
                       const float* __restrict__ bM, const float* __restrict__ bL,
                       const float* __restrict__ eps,
                       float* __restrict__ oI,
                       float* __restrict__ oM, float* __restrict__ oL,
                       float* __restrict__ z, int n) {
    int wid  = (int)((blockIdx.x * (size_t)blockDim.x + threadIdx.x) >> 6);
    int lane = threadIdx.x & 63;
    if (wid >= n) return;
    int half = lane >> 5;
    int q    = lane & 31;
    size_t rb = (size_t)wid * 128;
    const float* hq = h + 4 * q;

    float4 acc = make_float4(0.f, 0.f, 0.f, 0.f);
    if (half == 0) {
        float di = dis[wid];
        float self = di * di;
        float4 s4 = *(const float4*)&hq[rb];
        acc.x = s4.x * self; acc.y = s4.y * self;
        acc.z = s4.z * self; acc.w = s4.w * self;
    }

    int beg = row_ptr[wid], end = row_ptr[wid + 1];
    for (int cb = beg; cb < end; cb += 64) {
        int m = end - cb;
        if (m > 64) m = 64;
        int sv = 0; float nv = 0.f;
        if (lane < m) { sv = srcs[cb + lane]; nv = norms[cb + lane]; }
        int j = 0;
        for (; j + 4 <= m; j += 4) {
            int   sA = __shfl(sv, j + half, 64);
            float wA = __shfl(nv, j + half, 64);
            int   sB = __shfl(sv, j + 2 + half, 64);
            float wB = __shfl(nv, j + 2 + half, 64);
            float4 vA = *(const float4*)&hq[(size_t)sA * 128];
            float4 vB = *(const float4*)&hq[(size_t)sB * 128];
            acc.x = fmaf(vA.x, wA, acc.x); acc.y = fmaf(vA.y, wA, acc.y);
            acc.z = fmaf(vA.z, wA, acc.z); acc.w = fmaf(vA.w, wA, acc.w);
            acc.x = fmaf(vB.x, wB, acc.x); acc.y = fmaf(vB.y, wB, acc.y);
            acc.z = fmaf(vB.z, wB, acc.z); acc.w = fmaf(vB.w, wB, acc.w);
        }
        for (; j + 2 <= m; j += 2) {
            int   sA = __shfl(sv, j + half, 64);
            float wA = __shfl(nv, j + half, 64);
            float4 vA = *(const float4*)&hq[(size_t)sA * 128];
            acc.x = fmaf(vA.x, wA, acc.x); acc.y = fmaf(vA.y, wA, acc.y);
            acc.z = fmaf(vA.z, wA, acc.z); acc.w = fmaf(vA.w, wA, acc.w);
        }
        if (j < m) {
            int   sA = __shfl(sv, j, 64);
            float wA = __shfl(nv, j, 64);
            if (half == 0) {
                float4 vA = *(const float4*)&hq[(size_t)sA * 128];
                acc.x = fmaf(vA.x, wA, acc.x); acc.y = fmaf(vA.y, wA, acc.y);
                acc.z = fmaf(vA.z, wA, acc.z); acc.w = fmaf(vA.w, wA, acc.w);
            }
        }
    }

    // cross-half reduction: both halves end with the full sum
    acc.x += __shfl_xor(acc.x, 32, 64);
    acc.y += __shfl_xor(acc.y, 32, 64);
    acc.z += __shfl_xor(acc.z, 32, 64);
    acc.w += __shfl_xor(acc.w, 32, 64);

    if (MODE == 0) {
        if (half == 0) *(float4*)&oI[rb + 4 * q] = acc;
    } else if (MODE == 1) {
        if (half == 0) {
            float4 b = (q < 16) ? ((const float4*)bM)[q] : ((const float4*)bL)[q - 16];
            acc.x = fmaxf(acc.x + b.x, 0.f);
            acc.y = fmaxf(acc.y + b.y, 0.f);
            acc.z = fmaxf(acc.z + b.z, 0.f);
            acc.w = fmaxf(acc.w + b.w, 0.f);
            *(float4*)&oI[rb + 4 * q] = acc;
        }
    } else {
        // all lanes compute their post-activation value (mu or ls channels)
        float4 b = (q < 16) ? ((const float4*)bM)[q] : ((const float4*)bL)[q - 16];
        float4 act;
        act.x = fmaxf(acc.x + b.x, 0.f);
        act.y = fmaxf(acc.y + b.y, 0.f);
        act.z = fmaxf(acc.z + b.z, 0.f);
        act.w = fmaxf(acc.w + b.w, 0.f);
        if (q >= 16) {
            act.x = fminf(act.x, 10.f); act.y = fminf(act.y, 10.f);
            act.z = fminf(act.z, 10.f); act.w = fminf(act.w, 10.f);
        }
        // pull ls channels (held at lane+16) into mu lanes for z
        float4 ls;
        ls.x = __shfl(act.x, lane + 16, 64);
        ls.y = __shfl(act.y, lane + 16, 64);
        ls.z = __shfl(act.z, lane + 16, 64);
        ls.w = __shfl(act.w, lane + 16, 64);
        if (half == 0) {
            size_t ob = (size_t)wid * 64;
            if (q < 16) {
                ((float4*)&oM[ob])[q] = act;
                float4 e = ((const float4*)&eps[ob])[q];
                float4 zz;
                zz.x = fmaf(e.x, expf(ls.x), act.x);
                zz.y = fmaf(e.y, expf(ls.y), act.y);
                zz.z = fmaf(e.z, expf(ls.z), act.z);
                zz.w = fmaf(e.w, expf(ls.w), act.w);
                ((float4*)&z[ob])[q] = zz;
            } else {
                ((float4*)&oL[ob])[q - 16] = act;
            }
        }
    }
}

// adj[e] = sigmoid( dot(z[src], z[dst]) ): 16 lanes per edge, float4 per lane
__global__ void decoder_k(const int* __restrict__ ei, const float* __restrict__ z,
                          float* __restrict__ adj, int E) {
    int t = blockIdx.x * 256 + threadIdx.x;
    int e = t >> 4;
    int q = threadIdx.x & 15;
    if (e >= E) return;
    int s = ei[e];
    int d = ei[E + e];
    const float4* z4 = (const float4*)z;
    float4 a = z4[(size_t)s * 16 + q];
    float4 b = z4[(size_t)d * 16 + q];
    float p = a.x * b.x + a.y * b.y + a.z * b.z + a.w * b.w;
    p += __shfl_xor(p, 8);
    p += __shfl_xor(p, 4);
    p += __shfl_xor(p, 2);
    p += __shfl_xor(p, 1);
    if (q == 0) adj[e] = 1.f / (1.f + expf(-p));
}

extern "C" void kernel_launch(void* const* d_in, const int* in_sizes, int n_in,
                              void* d_out, int out_size, void* d_ws, size_t ws_size,
                              hipStream_t stream) {
    const float* x   = (const float*)d_in[0];
    const int*   ei  = (const int*)d_in[1];
    const float* eps = (const float*)d_in[2];
    const float* w_mu1 = (const float*)d_in[3];
    const float* b_mu1 = (const float*)d_in[4];
    const float* w_mu2 = (const float*)d_in[5];
    const float* b_mu2 = (const float*)d_in[6];
    const float* w_mu3 = (const float*)d_in[7];
    const float* b_mu3 = (const float*)d_in[8];
    const float* w_ls1 = (const float*)d_in[9];
    const float* b_ls1 = (const float*)d_in[10];
    const float* w_ls2 = (const float*)d_in[11];
    const float* b_ls2 = (const float*)d_in[12];
    const float* w_ls3 = (const float*)d_in[13];
    const float* b_ls3 = (const float*)d_in[14];

    const int N = in_sizes[0] / 128;
    const int E = in_sizes[1] / 2;
    const size_t NB = (size_t)N * 128;

    float* out = (float*)d_out;
    float* adj = out;                        // [E]
    float* mu  = out + E;                    // [N*64]
    float* ls  = out + E + (size_t)N * 64;   // [N*64]
    float* M   = out + E;                    // mu|ls region doubles as N*128 scratch

    float* ws = (float*)d_ws;
    const size_t P  = 50176;   // >= N+1
    const size_t EP = 600064;  // >= E
    float* R1 = ws;
    float* R3 = ws + NB;
    float* c0 = ws + 2 * NB;
    float* dis         = c0;
    int*   cnt         = (int*)(c0 + P);
    int*   row_ptr     = (int*)(c0 + 2 * P);
    int*   woff        = (int*)(c0 + 3 * P);
    int*   bsum        = (int*)(c0 + 4 * P);           // <=64 block sums
    int*   src_sorted  = (int*)(c0 + 4 * P + 256);
    float* norm_sorted = c0 + 4 * P + 256 + EP;

    const int nscan = (N + 1023) / 1024;  // 49 <= 64

    // ---- CSR build ----
    zero_int_k<<<(N + 255) / 256, 256, 0, stream>>>(cnt, N);
    count_dst_k<<<(E + 255) / 256, 256, 0, stream>>>(ei, cnt, E);
    compute_dis_k<<<(N + 255) / 256, 256, 0, stream>>>(cnt, dis, N);
    scan1_k<<<nscan, 1024, 0, stream>>>(cnt, row_ptr, bsum, N);
    scan2_k<<<1, 64, 0, stream>>>(bsum, nscan);
    scan3_k<<<nscan, 1024, 0, stream>>>(cnt, row_ptr, bsum, woff, N);
    scatter_edges_k<<<(E + 255) / 256, 256, 0, stream>>>(ei, dis, woff, src_sorted,
                                                         norm_sorted, E);

    const int aggBlocks = (int)(((size_t)N * 64 + 255) / 256);
    dim3 g64((N + 63) / 64, 2), g32((N + 31) / 32, 2);

    // ---- layer 1: t1 = x@W1 (both branches, interleaved R1); h1 = relu(A t1 + b) -> M
    matmul2_k<128, 64, 0><<<g64, 256, 0, stream>>>(x, x, 128, 0, 0, w_mu1, w_ls1,
                                                   nullptr, nullptr, R1, R1, 128, 0, 64, N);
    agg2_k<1><<<aggBlocks, 256, 0, stream>>>(R1, dis, row_ptr, src_sorted, norm_sorted,
                                             b_mu1, b_ls1, nullptr, M, nullptr, nullptr,
                                             nullptr, N);

    // ---- layer 2 (reordered): a2 = A h1 -> R1;  h2 = relu(a2@W2 + b2) -> M / R3
    agg2_k<0><<<aggBlocks, 256, 0, stream>>>(M, dis, row_ptr, src_sorted, norm_sorted,
                                             nullptr, nullptr, nullptr, R1, nullptr,
                                             nullptr, nullptr, N);
    matmul2_k<64, 128, 1><<<g32, 256, 0, stream>>>(R1, R1, 128, 0, 64, w_mu2, w_ls2,
                                                   b_mu2, b_ls2, M, R3, 128, 0, 0, N);

    // ---- layer 3: m3 = h2@W3 (interleaved R1); final agg + z
    matmul2_k<128, 64, 0><<<g64, 256, 0, stream>>>(M, R3, 128, 0, 0, w_mu3, w_ls3,
                                                   nullptr, nullptr, R1, R1, 128, 0, 64, N);
    agg2_k<2><<<aggBlocks, 256, 0, stream>>>(R1, dis, row_ptr, src_sorted, norm_sorted,
                                             b_mu3, b_ls3, eps, nullptr, mu, ls, R3, N);

    // ---- decode ----
    decoder_k<<<(int)(((size_t)E * 16 + 255) / 256), 256, 0, stream>>>(ei, R3, adj, E);
}

// Round 8
// 299.852 us; speedup vs baseline: 3.0898x; 1.3005x over previous
//
#include <hip/hip_runtime.h>
#include <hip/hip_bf16.h>
#include <hip/hip_fp16.h>
#include <math.h>

// ---------------------------------------------------------------------------
// GRAPH_VAE_V3: GCN-VAE encoder + inner-product decoder.
// R8: fp16 gather rows (halve agg HBM/L3 traffic), quad-edge uint4 gather,
// K-chunked matmul LDS (40KB -> 4 blocks/CU), fp32 accumulation everywhere.
// ---------------------------------------------------------------------------

__global__ void zero_int_k(int* __restrict__ p, int n) {
    int i = blockIdx.x * blockDim.x + threadIdx.x;
    if (i < n) p[i] = 0;
}

__global__ void count_dst_k(const int* __restrict__ ei, int* __restrict__ cnt, int E) {
    int e = blockIdx.x * blockDim.x + threadIdx.x;
    if (e < E) atomicAdd(&cnt[ei[E + e]], 1);
}

__global__ void compute_dis_k(const int* __restrict__ cnt, float* __restrict__ dis, int n) {
    int i = blockIdx.x * blockDim.x + threadIdx.x;
    if (i < n) dis[i] = rsqrtf((float)cnt[i] + 1.0f);
}

// ---- 3-phase parallel scan ----
__global__ void scan1_k(const int* __restrict__ cnt, int* __restrict__ row_ptr,
                        int* __restrict__ bsum, int n) {
    __shared__ int wsum[16];
    int tid = threadIdx.x, lane = tid & 63, wv = tid >> 6;
    int i = blockIdx.x * 1024 + tid;
    int v = (i < n) ? cnt[i] : 0;
    int x = v;
#pragma unroll
    for (int off = 1; off < 64; off <<= 1) {
        int t = __shfl_up(x, off, 64);
        if (lane >= off) x += t;
    }
    if (lane == 63) wsum[wv] = x;
    __syncthreads();
    if (wv == 0 && lane < 16) {
        int y = wsum[lane];
#pragma unroll
        for (int off = 1; off < 16; off <<= 1) {
            int t = __shfl_up(y, off, 64);
            if (lane >= off) y += t;
        }
        wsum[lane] = y;
    }
    __syncthreads();
    int incl = x + ((wv == 0) ? 0 : wsum[wv - 1]);
    if (i < n) row_ptr[i + 1] = incl;
    if (tid == 1023) bsum[blockIdx.x] = incl;
}

__global__ void scan2_k(int* __restrict__ bsum, int nb) {
    int lane = threadIdx.x;
    int v = (lane < nb) ? bsum[lane] : 0;
    int x = v;
#pragma unroll
    for (int off = 1; off < 64; off <<= 1) {
        int t = __shfl_up(x, off, 64);
        if (lane >= off) x += t;
    }
    if (lane < nb) bsum[lane] = x - v;
}

__global__ void scan3_k(const int* __restrict__ cnt, int* __restrict__ row_ptr,
                        const int* __restrict__ bsum, int* __restrict__ woff, int n) {
    int i = blockIdx.x * 1024 + threadIdx.x;
    if (i == 0) row_ptr[0] = 0;
    if (i < n) {
        int r = row_ptr[i + 1] + bsum[blockIdx.x];
        row_ptr[i + 1] = r;
        woff[i] = r - cnt[i];
    }
}

__global__ void scatter_edges_k(const int* __restrict__ ei, const float* __restrict__ dis,
                                int* __restrict__ woff, int* __restrict__ src_sorted,
                                float* __restrict__ norm_sorted, int E) {
    int e = blockIdx.x * blockDim.x + threadIdx.x;
    if (e < E) {
        int s = ei[e];
        int d = ei[E + e];
        int pos = atomicAdd(&woff[d], 1);
        src_sorted[pos]  = s;
        norm_sorted[pos] = dis[s] * dis[d];
    }
}

// Branch-pair matmul, K-chunked A staging (KC=32).  blockIdx.y = branch.
// H16=1: write fp16 to HH at offh; else fp32 to HA/HB (+bias,relu if EPI).
template <int K, int OUT, int EPI, int H16>
__global__ __launch_bounds__(256, 4) void matmul2_k(
        const float* __restrict__ AA, const float* __restrict__ AB, int lda,
        int offaA, int offaB,
        const float* __restrict__ WA, const float* __restrict__ WB,
        const float* __restrict__ bA, const float* __restrict__ bB,
        float* __restrict__ HA, float* __restrict__ HB, __half* __restrict__ HH,
        int ldh, int offhA, int offhB, int n) {
    constexpr int TX = OUT / 4;
    constexpr int TY = 256 / TX;
    constexpr int TM = TY * 4;
    constexpr int KC = 32, KC4 = 8;
    __shared__ float w_lds[K * OUT];
    __shared__ float a_lds[TM * KC];

    int by = blockIdx.y;
    const float* A  = by ? AB : AA;
    const float* W  = by ? WB : WA;
    const float* bi = by ? bB : bA;
    float*       H  = by ? HB : HA;
    int offa = by ? offaB : offaA;
    int offh = by ? offhB : offhA;

    int tid = threadIdx.x;
    for (int idx = tid; idx < K * OUT / 4; idx += 256)
        ((float4*)w_lds)[idx] = ((const float4*)W)[idx];

    int row0 = blockIdx.x * TM;
    int tx = tid % TX;
    int ty = tid / TX;

    float4 acc[4];
#pragma unroll
    for (int i = 0; i < 4; ++i) acc[i] = make_float4(0.f, 0.f, 0.f, 0.f);

    int abase[4], akey[4];
#pragma unroll
    for (int i = 0; i < 4; ++i) {
        int r = ty * 4 + i;
        abase[i] = r * KC;
        akey[i]  = (r >> 2) & 7;  // distinct across the 4 stride-4 rows a wave reads
    }

    for (int kc = 0; kc < K; kc += KC) {
        __syncthreads();
        for (int f4 = tid; f4 < TM * KC4; f4 += 256) {
            int row  = f4 >> 3;
            int col4 = f4 & 7;
            float4 v = make_float4(0.f, 0.f, 0.f, 0.f);
            if (row0 + row < n)
                v = *(const float4*)&A[(size_t)(row0 + row) * lda + offa + kc + (col4 << 2)];
            *(float4*)&a_lds[row * KC + ((col4 ^ ((row >> 2) & 7)) << 2)] = v;
        }
        __syncthreads();

#pragma unroll
        for (int k = 0; k < KC; k += 4) {
            int k4 = k >> 2;
            float af[4][4];
#pragma unroll
            for (int i = 0; i < 4; ++i) {
                float4 a = *(const float4*)&a_lds[abase[i] + ((k4 ^ akey[i]) << 2)];
                af[i][0] = a.x; af[i][1] = a.y; af[i][2] = a.z; af[i][3] = a.w;
            }
#pragma unroll
            for (int j = 0; j < 4; ++j) {
                float4 wv = ((const float4*)w_lds)[(kc + k + j) * TX + tx];
#pragma unroll
                for (int i = 0; i < 4; ++i) {
                    acc[i].x += af[i][j] * wv.x;
                    acc[i].y += af[i][j] * wv.y;
                    acc[i].z += af[i][j] * wv.z;
                    acc[i].w += af[i][j] * wv.w;
                }
            }
        }
    }

#pragma unroll
    for (int i = 0; i < 4; ++i) {
        int r = row0 + ty * 4 + i;
        if (r < n) {
            float4 o = acc[i];
            if (EPI == 1) {
                float4 b = ((const float4*)bi)[tx];
                o.x = fmaxf(o.x + b.x, 0.f);
                o.y = fmaxf(o.y + b.y, 0.f);
                o.z = fmaxf(o.z + b.z, 0.f);
                o.w = fmaxf(o.w + b.w, 0.f);
            }
            if (H16) {
                __half2 h0 = __floats2half2_rn(o.x, o.y);
                __half2 h1 = __floats2half2_rn(o.z, o.w);
                uint2 u = make_uint2(*(unsigned*)&h0, *(unsigned*)&h1);
                *(uint2*)&HH[(size_t)r * ldh + offh + tx * 4] = u;
            } else {
                *(float4*)&H[(size_t)r * ldh + offh + tx * 4] = o;
            }
        }
    }
}

// Dual-branch CSR aggregation over fp16 rows [mu64|ls64] (256B).
// Wave: 4 edge-groups (g=lane>>4) x 16 channel-octets (q=lane&15).
// One uint4 gather instruction fetches 4 full rows.  fp32 accumulate.
// MODE 0: raw agg -> fp32 oI;  1: relu(agg+b) -> fp16 oH;
// MODE 2: mu=relu, ls=clamp(relu), z=mu+eps*exp(ls) -> oM,oL,z (fp32)
template <int MODE>
__global__ void agg2h_k(const __half* __restrict__ h, const float* __restrict__ dis,
                        const int* __restrict__ row_ptr, const int* __restrict__ srcs,
                        const float* __restrict__ norms,
                        const float* __restrict__ bM, const float* __restrict__ bL,
                        const float* __restrict__ eps,
                        __half* __restrict__ oH, float* __restrict__ oI,
                        float* __restrict__ oM, float* __restrict__ oL,
                        float* __restrict__ z, int n) {
    int wid  = (int)((blockIdx.x * (size_t)blockDim.x + threadIdx.x) >> 6);
    int lane = threadIdx.x & 63;
    if (wid >= n) return;
    int g = lane >> 4;   // edge sub-group
    int q = lane & 15;   // channel octet: owns channels 8q..8q+7
    const __half* hq = h + 8 * q;

    float acc[8];
#pragma unroll
    for (int i = 0; i < 8; ++i) acc[i] = 0.f;

    if (g == 0) {
        float di = dis[wid];
        float self = di * di;
        uint4 r = *(const uint4*)&hq[(size_t)wid * 128];
        const __half2* hp = (const __half2*)&r;
#pragma unroll
        for (int i = 0; i < 4; ++i) {
            float2 f = __half22float2(hp[i]);
            acc[2 * i]     = f.x * self;
            acc[2 * i + 1] = f.y * self;
        }
    }

    int beg = row_ptr[wid], end = row_ptr[wid + 1];
    for (int cb = beg; cb < end; cb += 64) {
        int m = end - cb;
        if (m > 64) m = 64;
        int sv = 0; float nv = 0.f;
        if (lane < m) { sv = srcs[cb + lane]; nv = norms[cb + lane]; }
        int j = 0;
        for (; j + 8 <= m; j += 8) {
            int   sA = __shfl(sv, j + g, 64);
            float wA = __shfl(nv, j + g, 64);
            int   sB = __shfl(sv, j + 4 + g, 64);
            float wB = __shfl(nv, j + 4 + g, 64);
            uint4 ra = *(const uint4*)&hq[(size_t)sA * 128];
            uint4 rb = *(const uint4*)&hq[(size_t)sB * 128];
            const __half2* pa = (const __half2*)&ra;
            const __half2* pb = (const __half2*)&rb;
#pragma unroll
            for (int i = 0; i < 4; ++i) {
                float2 fa = __half22float2(pa[i]);
                float2 fb = __half22float2(pb[i]);
                acc[2 * i]     = fmaf(fa.x, wA, acc[2 * i]);
                acc[2 * i + 1] = fmaf(fa.y, wA, acc[2 * i + 1]);
                acc[2 * i]     = fmaf(fb.x, wB, acc[2 * i]);
                acc[2 * i + 1] = fmaf(fb.y, wB, acc[2 * i + 1]);
            }
        }
        for (; j < m; j += 4) {
            int idx = j + g;
            int   sA = __shfl(sv, (idx < m) ? idx : j, 64);
            float wA = __shfl(nv, (idx < m) ? idx : j, 64);
            if (idx < m) {
                uint4 ra = *(const uint4*)&hq[(size_t)sA * 128];
                const __half2* pa = (const __half2*)&ra;
#pragma unroll
                for (int i = 0; i < 4; ++i) {
                    float2 fa = __half22float2(pa[i]);
                    acc[2 * i]     = fmaf(fa.x, wA, acc[2 * i]);
                    acc[2 * i + 1] = fmaf(fa.y, wA, acc[2 * i + 1]);
                }
            }
        }
    }

    // combine the 4 edge-groups: every lane ends with the full channel sums
#pragma unroll
    for (int i = 0; i < 8; ++i) {
        acc[i] += __shfl_xor(acc[i], 16, 64);
        acc[i] += __shfl_xor(acc[i], 32, 64);
    }

    if (MODE == 0) {
        if (g == 0) {
            size_t rb = (size_t)wid * 128 + 8 * q;
            *(float4*)&oI[rb]     = make_float4(acc[0], acc[1], acc[2], acc[3]);
            *(float4*)&oI[rb + 4] = make_float4(acc[4], acc[5], acc[6], acc[7]);
        }
    } else if (MODE == 1) {
        if (g == 0) {
            const float* bs = (q < 8) ? bM + 8 * q : bL + 8 * q - 64;
            __half2 hh[4];
#pragma unroll
            for (int i = 0; i < 8; i += 2) {
                float a0 = fmaxf(acc[i] + bs[i], 0.f);
                float a1 = fmaxf(acc[i + 1] + bs[i + 1], 0.f);
                hh[i >> 1] = __floats2half2_rn(a0, a1);
            }
            *(uint4*)&oH[(size_t)wid * 128 + 8 * q] = *(uint4*)hh;
        }
    } else {
        const float* bs = (q < 8) ? bM + 8 * q : bL + 8 * q - 64;
        float act[8];
#pragma unroll
        for (int i = 0; i < 8; ++i) {
            float a = fmaxf(acc[i] + bs[i], 0.f);
            if (q >= 8) a = fminf(a, 10.f);
            act[i] = a;
        }
        float lsv[8];
#pragma unroll
        for (int i = 0; i < 8; ++i) lsv[i] = __shfl(act[i], lane + 8, 64);
        if (g == 0) {
            size_t ob = (size_t)wid * 64;
            if (q < 8) {
                *(float4*)&oM[ob + 8 * q]     = make_float4(act[0], act[1], act[2], act[3]);
                *(float4*)&oM[ob + 8 * q + 4] = make_float4(act[4], act[5], act[6], act[7]);
                float4 e0 = *(const float4*)&eps[ob + 8 * q];
                float4 e1 = *(const float4*)&eps[ob + 8 * q + 4];
                float4 z0, z1;
                z0.x = fmaf(e0.x, expf(lsv[0]), act[0]);
                z0.y = fmaf(e0.y, expf(lsv[1]), act[1]);
                z0.z = fmaf(e0.z, expf(lsv[2]), act[2]);
                z0.w = fmaf(e0.w, expf(lsv[3]), act[3]);
                z1.x = fmaf(e1.x, expf(lsv[4]), act[4]);
                z1.y = fmaf(e1.y, expf(lsv[5]), act[5]);
                z1.z = fmaf(e1.z, expf(lsv[6]), act[6]);
                z1.w = fmaf(e1.w, expf(lsv[7]), act[7]);
                *(float4*)&z[ob + 8 * q]     = z0;
                *(float4*)&z[ob + 8 * q + 4] = z1;
            } else {
                int qq = q - 8;
                *(float4*)&oL[ob + 8 * qq]     = make_float4(act[0], act[1], act[2], act[3]);
                *(float4*)&oL[ob + 8 * qq + 4] = make_float4(act[4], act[5], act[6], act[7]);
            }
        }
    }
}

// adj[e] = sigmoid( dot(z[src], z[dst]) ): 16 lanes per edge, float4 per lane
__global__ void decoder_k(const int* __restrict__ ei, const float* __restrict__ z,
                          float* __restrict__ adj, int E) {
    int t = blockIdx.x * 256 + threadIdx.x;
    int e = t >> 4;
    int q = threadIdx.x & 15;
    if (e >= E) return;
    int s = ei[e];
    int d = ei[E + e];
    const float4* z4 = (const float4*)z;
    float4 a = z4[(size_t)s * 16 + q];
    float4 b = z4[(size_t)d * 16 + q];
    float p = a.x * b.x + a.y * b.y + a.z * b.z + a.w * b.w;
    p += __shfl_xor(p, 8);
    p += __shfl_xor(p, 4);
    p += __shfl_xor(p, 2);
    p += __shfl_xor(p, 1);
    if (q == 0) adj[e] = 1.f / (1.f + expf(-p));
}

extern "C" void kernel_launch(void* const* d_in, const int* in_sizes, int n_in,
                              void* d_out, int out_size, void* d_ws, size_t ws_size,
                              hipStream_t stream) {
    const float* x   = (const float*)d_in[0];
    const int*   ei  = (const int*)d_in[1];
    const float* eps = (const float*)d_in[2];
    const float* w_mu1 = (const float*)d_in[3];
    const float* b_mu1 = (const float*)d_in[4];
    const float* w_mu2 = (const float*)d_in[5];
    const float* b_mu2 = (const float*)d_in[6];
    const float* w_mu3 = (const float*)d_in[7];
    const float* b_mu3 = (const float*)d_in[8];
    const float* w_ls1 = (const float*)d_in[9];
    const float* b_ls1 = (const float*)d_in[10];
    const float* w_ls2 = (const float*)d_in[11];
    const float* b_ls2 = (const float*)d_in[12];
    const float* w_ls3 = (const float*)d_in[13];
    const float* b_ls3 = (const float*)d_in[14];

    const int N = in_sizes[0] / 128;
    const int E = in_sizes[1] / 2;
    const size_t NB = (size_t)N * 128;

    float* out = (float*)d_out;
    float* adj = out;                        // [E]
    float* mu  = out + E;                    // [N*64]
    float* ls  = out + E + (size_t)N * 64;   // [N*64]
    float* M   = out + E;                    // mu|ls region doubles as N*128 fp32 scratch

    // region X:  hpA (fp16 N*128, mm1/mm3 out) then R1 (fp32 N*128, agg2 out) — disjoint in time
    // region Y:  hpB (fp16 N*128, agg1 out) then R3 (fp32 N*128, mm2 out) then z (fp32 N*64)
    float* ws = (float*)d_ws;
    float*  R1  = ws;
    __half* hpA = (__half*)ws;
    float*  R3  = ws + NB;
    __half* hpB = (__half*)(ws + NB);
    float*  zb  = ws + NB;                   // z reuses R3 region after mm3
    float* c0 = ws + 2 * NB;
    const size_t P  = 50176;   // >= N+1
    const size_t EP = 600064;  // >= E
    float* dis         = c0;
    int*   cnt         = (int*)(c0 + P);
    int*   row_ptr     = (int*)(c0 + 2 * P);
    int*   woff        = (int*)(c0 + 3 * P);
    int*   bsum        = (int*)(c0 + 4 * P);
    int*   src_sorted  = (int*)(c0 + 4 * P + 256);
    float* norm_sorted = c0 + 4 * P + 256 + EP;

    const int nscan = (N + 1023) / 1024;

    // ---- CSR build ----
    zero_int_k<<<(N + 255) / 256, 256, 0, stream>>>(cnt, N);
    count_dst_k<<<(E + 255) / 256, 256, 0, stream>>>(ei, cnt, E);
    compute_dis_k<<<(N + 255) / 256, 256, 0, stream>>>(cnt, dis, N);
    scan1_k<<<nscan, 1024, 0, stream>>>(cnt, row_ptr, bsum, N);
    scan2_k<<<1, 64, 0, stream>>>(bsum, nscan);
    scan3_k<<<nscan, 1024, 0, stream>>>(cnt, row_ptr, bsum, woff, N);
    scatter_edges_k<<<(E + 255) / 256, 256, 0, stream>>>(ei, dis, woff, src_sorted,
                                                         norm_sorted, E);

    const int aggBlocks = (int)(((size_t)N * 64 + 255) / 256);
    dim3 g64((N + 63) / 64, 2), g32((N + 31) / 32, 2);

    // layer 1: t1 = x@W1 (fp16, interleaved hpA);  h1 = relu(A t1 + b) -> hpB (fp16)
    matmul2_k<128, 64, 0, 1><<<g64, 256, 0, stream>>>(x, x, 128, 0, 0, w_mu1, w_ls1,
                                                      nullptr, nullptr, nullptr, nullptr,
                                                      hpA, 128, 0, 64, N);
    agg2h_k<1><<<aggBlocks, 256, 0, stream>>>(hpA, dis, row_ptr, src_sorted, norm_sorted,
                                              b_mu1, b_ls1, nullptr, hpB, nullptr,
                                              nullptr, nullptr, nullptr, N);

    // layer 2 (reordered): a2 = A h1 -> R1 (fp32);  h2 = relu(a2@W2 + b2) -> M / R3 (fp32)
    agg2h_k<0><<<aggBlocks, 256, 0, stream>>>(hpB, dis, row_ptr, src_sorted, norm_sorted,
                                              nullptr, nullptr, nullptr, nullptr, R1,
                                              nullptr, nullptr, nullptr, N);
    matmul2_k<64, 128, 1, 0><<<g32, 256, 0, stream>>>(R1, R1, 128, 0, 64, w_mu2, w_ls2,
                                                      b_mu2, b_ls2, M, R3, nullptr,
                                                      128, 0, 0, N);

    // layer 3: m3 = h2@W3 (fp16, interleaved hpA);  final agg -> mu, ls, z
    matmul2_k<128, 64, 0, 1><<<g64, 256, 0, stream>>>(M, R3, 128, 0, 0, w_mu3, w_ls3,
                                                      nullptr, nullptr, nullptr, nullptr,
                                                      hpA, 128, 0, 64, N);
    agg2h_k<2><<<aggBlocks, 256, 0, stream>>>(hpA, dis, row_ptr, src_sorted, norm_sorted,
                                              b_mu3, b_ls3, eps, nullptr, nullptr,
                                              mu, ls, zb, N);

    // decode
    decoder_k<<<(int)(((size_t)E * 16 + 255) / 256), 256, 0, stream>>>(ei, zb, adj, E);
}

// Round 9
// 283.789 us; speedup vs baseline: 3.2647x; 1.0566x over previous
//
#include <hip/hip_runtime.h>
#include <hip/hip_bf16.h>
#include <hip/hip_fp16.h>
#include <math.h>

// ---------------------------------------------------------------------------
// GRAPH_VAE_V3: GCN-VAE encoder + inner-product decoder.
// R9: dis-prescaled gather rows => norm array eliminated (scatter writes 4B/edge,
// agg loop is a pure unweighted sum), fp16 z for decoder gathers.
// ---------------------------------------------------------------------------

__global__ void zero_int_k(int* __restrict__ p, int n) {
    int i = blockIdx.x * blockDim.x + threadIdx.x;
    if (i < n) p[i] = 0;
}

__global__ void count_dst_k(const int* __restrict__ ei, int* __restrict__ cnt, int E) {
    int e = blockIdx.x * blockDim.x + threadIdx.x;
    if (e < E) atomicAdd(&cnt[ei[E + e]], 1);
}

__global__ void compute_dis_k(const int* __restrict__ cnt, float* __restrict__ dis, int n) {
    int i = blockIdx.x * blockDim.x + threadIdx.x;
    if (i < n) dis[i] = rsqrtf((float)cnt[i] + 1.0f);
}

// ---- 3-phase parallel scan ----
__global__ void scan1_k(const int* __restrict__ cnt, int* __restrict__ row_ptr,
                        int* __restrict__ bsum, int n) {
    __shared__ int wsum[16];
    int tid = threadIdx.x, lane = tid & 63, wv = tid >> 6;
    int i = blockIdx.x * 1024 + tid;
    int v = (i < n) ? cnt[i] : 0;
    int x = v;
#pragma unroll
    for (int off = 1; off < 64; off <<= 1) {
        int t = __shfl_up(x, off, 64);
        if (lane >= off) x += t;
    }
    if (lane == 63) wsum[wv] = x;
    __syncthreads();
    if (wv == 0 && lane < 16) {
        int y = wsum[lane];
#pragma unroll
        for (int off = 1; off < 16; off <<= 1) {
            int t = __shfl_up(y, off, 64);
            if (lane >= off) y += t;
        }
        wsum[lane] = y;
    }
    __syncthreads();
    int incl = x + ((wv == 0) ? 0 : wsum[wv - 1]);
    if (i < n) row_ptr[i + 1] = incl;
    if (tid == 1023) bsum[blockIdx.x] = incl;
}

__global__ void scan2_k(int* __restrict__ bsum, int nb) {
    int lane = threadIdx.x;
    int v = (lane < nb) ? bsum[lane] : 0;
    int x = v;
#pragma unroll
    for (int off = 1; off < 64; off <<= 1) {
        int t = __shfl_up(x, off, 64);
        if (lane >= off) x += t;
    }
    if (lane < nb) bsum[lane] = x - v;
}

__global__ void scan3_k(const int* __restrict__ cnt, int* __restrict__ row_ptr,
                        const int* __restrict__ bsum, int* __restrict__ woff, int n) {
    int i = blockIdx.x * 1024 + threadIdx.x;
    if (i == 0) row_ptr[0] = 0;
    if (i < n) {
        int r = row_ptr[i + 1] + bsum[blockIdx.x];
        row_ptr[i + 1] = r;
        woff[i] = r - cnt[i];
    }
}

// scatter: only the src index (4B/edge) — norm eliminated by dis-prescaling
__global__ void scatter_edges_k(const int* __restrict__ ei, int* __restrict__ woff,
                                int* __restrict__ src_sorted, int E) {
    int e = blockIdx.x * blockDim.x + threadIdx.x;
    if (e < E) {
        int s = ei[e];
        int d = ei[E + e];
        int pos = atomicAdd(&woff[d], 1);
        src_sorted[pos] = s;
    }
}

// Branch-pair matmul, K-chunked A staging (KC=32).  blockIdx.y = branch.
// H16=1: write fp16 (x dis[r] prescale) to HH; else fp32 (+bias,relu if EPI).
template <int K, int OUT, int EPI, int H16>
__global__ __launch_bounds__(256, 4) void matmul2_k(
        const float* __restrict__ AA, const float* __restrict__ AB, int lda,
        int offaA, int offaB,
        const float* __restrict__ WA, const float* __restrict__ WB,
        const float* __restrict__ bA, const float* __restrict__ bB,
        float* __restrict__ HA, float* __restrict__ HB, __half* __restrict__ HH,
        const float* __restrict__ dis,
        int ldh, int offhA, int offhB, int n) {
    constexpr int TX = OUT / 4;
    constexpr int TY = 256 / TX;
    constexpr int TM = TY * 4;
    constexpr int KC = 32, KC4 = 8;
    __shared__ float w_lds[K * OUT];
    __shared__ float a_lds[TM * KC];

    int by = blockIdx.y;
    const float* A  = by ? AB : AA;
    const float* W  = by ? WB : WA;
    const float* bi = by ? bB : bA;
    float*       H  = by ? HB : HA;
    int offa = by ? offaB : offaA;
    int offh = by ? offhB : offhA;

    int tid = threadIdx.x;
    for (int idx = tid; idx < K * OUT / 4; idx += 256)
        ((float4*)w_lds)[idx] = ((const float4*)W)[idx];

    int row0 = blockIdx.x * TM;
    int tx = tid % TX;
    int ty = tid / TX;

    float4 acc[4];
#pragma unroll
    for (int i = 0; i < 4; ++i) acc[i] = make_float4(0.f, 0.f, 0.f, 0.f);

    int abase[4], akey[4];
#pragma unroll
    for (int i = 0; i < 4; ++i) {
        int r = ty * 4 + i;
        abase[i] = r * KC;
        akey[i]  = (r >> 2) & 7;
    }

    for (int kc = 0; kc < K; kc += KC) {
        __syncthreads();
        for (int f4 = tid; f4 < TM * KC4; f4 += 256) {
            int row  = f4 >> 3;
            int col4 = f4 & 7;
            float4 v = make_float4(0.f, 0.f, 0.f, 0.f);
            if (row0 + row < n)
                v = *(const float4*)&A[(size_t)(row0 + row) * lda + offa + kc + (col4 << 2)];
            *(float4*)&a_lds[row * KC + ((col4 ^ ((row >> 2) & 7)) << 2)] = v;
        }
        __syncthreads();

#pragma unroll
        for (int k = 0; k < KC; k += 4) {
            int k4 = k >> 2;
            float af[4][4];
#pragma unroll
            for (int i = 0; i < 4; ++i) {
                float4 a = *(const float4*)&a_lds[abase[i] + ((k4 ^ akey[i]) << 2)];
                af[i][0] = a.x; af[i][1] = a.y; af[i][2] = a.z; af[i][3] = a.w;
            }
#pragma unroll
            for (int j = 0; j < 4; ++j) {
                float4 wv = ((const float4*)w_lds)[(kc + k + j) * TX + tx];
#pragma unroll
                for (int i = 0; i < 4; ++i) {
                    acc[i].x += af[i][j] * wv.x;
                    acc[i].y += af[i][j] * wv.y;
                    acc[i].z += af[i][j] * wv.z;
                    acc[i].w += af[i][j] * wv.w;
                }
            }
        }
    }

#pragma unroll
    for (int i = 0; i < 4; ++i) {
        int r = row0 + ty * 4 + i;
        if (r < n) {
            float4 o = acc[i];
            if (EPI == 1) {
                float4 b = ((const float4*)bi)[tx];
                o.x = fmaxf(o.x + b.x, 0.f);
                o.y = fmaxf(o.y + b.y, 0.f);
                o.z = fmaxf(o.z + b.z, 0.f);
                o.w = fmaxf(o.w + b.w, 0.f);
            }
            if (H16) {
                float dsc = dis[r];  // prescale gather rows by dis
                __half2 h0 = __floats2half2_rn(o.x * dsc, o.y * dsc);
                __half2 h1 = __floats2half2_rn(o.z * dsc, o.w * dsc);
                uint2 u = make_uint2(*(unsigned*)&h0, *(unsigned*)&h1);
                *(uint2*)&HH[(size_t)r * ldh + offh + tx * 4] = u;
            } else {
                *(float4*)&H[(size_t)r * ldh + offh + tx * 4] = o;
            }
        }
    }
}

// Dual-branch CSR aggregation over dis-prescaled fp16 rows [mu64|ls64] (256B).
// Pure unweighted sum: S_d = sum_{s in N(d)} G'_s + G'_d;  agg_out = dis_d * S_d.
// Wave: 4 edge-groups (g) x 16 channel-octets (q).  fp32 accumulate.
// MODE 0: dis*S -> fp32 oI
// MODE 1: h=relu(dis*S+b); store fp16 h*dis (prescaled for next gather)
// MODE 2: mu=relu(dis*S+b), ls=clamp, z=mu+eps*exp(ls) -> fp32 oM,oL + fp16 zh
template <int MODE>
__global__ void agg2h_k(const __half* __restrict__ h, const float* __restrict__ dis,
                        const int* __restrict__ row_ptr, const int* __restrict__ srcs,
                        const float* __restrict__ bM, const float* __restrict__ bL,
                        const float* __restrict__ eps,
                        __half* __restrict__ oH, float* __restrict__ oI,
                        float* __restrict__ oM, float* __restrict__ oL,
                        __half* __restrict__ zh, int n) {
    int wid  = (int)((blockIdx.x * (size_t)blockDim.x + threadIdx.x) >> 6);
    int lane = threadIdx.x & 63;
    if (wid >= n) return;
    int g = lane >> 4;   // edge sub-group
    int q = lane & 15;   // channel octet: owns channels 8q..8q+7
    const __half* hq = h + 8 * q;

    float acc[8];
#pragma unroll
    for (int i = 0; i < 8; ++i) acc[i] = 0.f;

    if (g == 0) {  // self-loop term: + G'_d (already prescaled)
        uint4 r = *(const uint4*)&hq[(size_t)wid * 128];
        const __half2* hp = (const __half2*)&r;
#pragma unroll
        for (int i = 0; i < 4; ++i) {
            float2 f = __half22float2(hp[i]);
            acc[2 * i]     = f.x;
            acc[2 * i + 1] = f.y;
        }
    }

    int beg = row_ptr[wid], end = row_ptr[wid + 1];
    for (int cb = beg; cb < end; cb += 64) {
        int m = end - cb;
        if (m > 64) m = 64;
        int sv = 0;
        if (lane < m) sv = srcs[cb + lane];
        int j = 0;
        for (; j + 8 <= m; j += 8) {
            int sA = __shfl(sv, j + g, 64);
            int sB = __shfl(sv, j + 4 + g, 64);
            uint4 ra = *(const uint4*)&hq[(size_t)sA * 128];
            uint4 rb = *(const uint4*)&hq[(size_t)sB * 128];
            const __half2* pa = (const __half2*)&ra;
            const __half2* pb = (const __half2*)&rb;
#pragma unroll
            for (int i = 0; i < 4; ++i) {
                float2 fa = __half22float2(pa[i]);
                float2 fb = __half22float2(pb[i]);
                acc[2 * i]     += fa.x + fb.x;
                acc[2 * i + 1] += fa.y + fb.y;
            }
        }
        for (; j < m; j += 4) {
            int idx = j + g;
            int sA = __shfl(sv, (idx < m) ? idx : j, 64);
            if (idx < m) {
                uint4 ra = *(const uint4*)&hq[(size_t)sA * 128];
                const __half2* pa = (const __half2*)&ra;
#pragma unroll
                for (int i = 0; i < 4; ++i) {
                    float2 fa = __half22float2(pa[i]);
                    acc[2 * i]     += fa.x;
                    acc[2 * i + 1] += fa.y;
                }
            }
        }
    }

    // combine the 4 edge-groups
#pragma unroll
    for (int i = 0; i < 8; ++i) {
        acc[i] += __shfl_xor(acc[i], 16, 64);
        acc[i] += __shfl_xor(acc[i], 32, 64);
    }

    float di = dis[wid];
#pragma unroll
    for (int i = 0; i < 8; ++i) acc[i] *= di;   // agg_out = dis_d * S

    if (MODE == 0) {
        if (g == 0) {
            size_t rb = (size_t)wid * 128 + 8 * q;
            *(float4*)&oI[rb]     = make_float4(acc[0], acc[1], acc[2], acc[3]);
            *(float4*)&oI[rb + 4] = make_float4(acc[4], acc[5], acc[6], acc[7]);
        }
    } else if (MODE == 1) {
        if (g == 0) {
            const float* bs = (q < 8) ? bM + 8 * q : bL + 8 * q - 64;
            __half2 hh[4];
#pragma unroll
            for (int i = 0; i < 8; i += 2) {
                float a0 = fmaxf(acc[i] + bs[i], 0.f) * di;      // prescale for next gather
                float a1 = fmaxf(acc[i + 1] + bs[i + 1], 0.f) * di;
                hh[i >> 1] = __floats2half2_rn(a0, a1);
            }
            *(uint4*)&oH[(size_t)wid * 128 + 8 * q] = *(uint4*)hh;
        }
    } else {
        const float* bs = (q < 8) ? bM + 8 * q : bL + 8 * q - 64;
        float act[8];
#pragma unroll
        for (int i = 0; i < 8; ++i) {
            float a = fmaxf(acc[i] + bs[i], 0.f);
            if (q >= 8) a = fminf(a, 10.f);
            act[i] = a;
        }
        float lsv[8];
#pragma unroll
        for (int i = 0; i < 8; ++i) lsv[i] = __shfl(act[i], lane + 8, 64);
        if (g == 0) {
            size_t ob = (size_t)wid * 64;
            if (q < 8) {
                *(float4*)&oM[ob + 8 * q]     = make_float4(act[0], act[1], act[2], act[3]);
                *(float4*)&oM[ob + 8 * q + 4] = make_float4(act[4], act[5], act[6], act[7]);
                float4 e0 = *(const float4*)&eps[ob + 8 * q];
                float4 e1 = *(const float4*)&eps[ob + 8 * q + 4];
                float zz[8];
                zz[0] = fmaf(e0.x, expf(lsv[0]), act[0]);
                zz[1] = fmaf(e0.y, expf(lsv[1]), act[1]);
                zz[2] = fmaf(e0.z, expf(lsv[2]), act[2]);
                zz[3] = fmaf(e0.w, expf(lsv[3]), act[3]);
                zz[4] = fmaf(e1.x, expf(lsv[4]), act[4]);
                zz[5] = fmaf(e1.y, expf(lsv[5]), act[5]);
                zz[6] = fmaf(e1.z, expf(lsv[6]), act[6]);
                zz[7] = fmaf(e1.w, expf(lsv[7]), act[7]);
                __half2 zh4[4];
#pragma unroll
                for (int i = 0; i < 4; ++i) zh4[i] = __floats2half2_rn(zz[2 * i], zz[2 * i + 1]);
                *(uint4*)&zh[ob + 8 * q] = *(uint4*)zh4;
            } else {
                int qq = q - 8;
                *(float4*)&oL[ob + 8 * qq]     = make_float4(act[0], act[1], act[2], act[3]);
                *(float4*)&oL[ob + 8 * qq + 4] = make_float4(act[4], act[5], act[6], act[7]);
            }
        }
    }
}

// adj[e] = sigmoid( dot(z[src], z[dst]) ): 16 lanes/edge, fp16 z rows (128B)
__global__ void decoder_k(const int* __restrict__ ei, const __half* __restrict__ zh,
                          float* __restrict__ adj, int E) {
    int t = blockIdx.x * 256 + threadIdx.x;
    int e = t >> 4;
    int q = threadIdx.x & 15;
    if (e >= E) return;
    int s = ei[e];
    int d = ei[E + e];
    const uint2* z2 = (const uint2*)zh;
    uint2 ua = z2[(size_t)s * 16 + q];
    uint2 ub = z2[(size_t)d * 16 + q];
    const __half2* pa = (const __half2*)&ua;
    const __half2* pb = (const __half2*)&ub;
    float p = 0.f;
#pragma unroll
    for (int i = 0; i < 2; ++i) {
        float2 fa = __half22float2(pa[i]);
        float2 fb = __half22float2(pb[i]);
        p = fmaf(fa.x, fb.x, p);
        p = fmaf(fa.y, fb.y, p);
    }
    p += __shfl_xor(p, 8);
    p += __shfl_xor(p, 4);
    p += __shfl_xor(p, 2);
    p += __shfl_xor(p, 1);
    if (q == 0) adj[e] = 1.f / (1.f + expf(-p));
}

extern "C" void kernel_launch(void* const* d_in, const int* in_sizes, int n_in,
                              void* d_out, int out_size, void* d_ws, size_t ws_size,
                              hipStream_t stream) {
    const float* x   = (const float*)d_in[0];
    const int*   ei  = (const int*)d_in[1];
    const float* eps = (const float*)d_in[2];
    const float* w_mu1 = (const float*)d_in[3];
    const float* b_mu1 = (const float*)d_in[4];
    const float* w_mu2 = (const float*)d_in[5];
    const float* b_mu2 = (const float*)d_in[6];
    const float* w_mu3 = (const float*)d_in[7];
    const float* b_mu3 = (const float*)d_in[8];
    const float* w_ls1 = (const float*)d_in[9];
    const float* b_ls1 = (const float*)d_in[10];
    const float* w_ls2 = (const float*)d_in[11];
    const float* b_ls2 = (const float*)d_in[12];
    const float* w_ls3 = (const float*)d_in[13];
    const float* b_ls3 = (const float*)d_in[14];

    const int N = in_sizes[0] / 128;
    const int E = in_sizes[1] / 2;
    const size_t NB = (size_t)N * 128;

    float* out = (float*)d_out;
    float* adj = out;                        // [E]
    float* mu  = out + E;                    // [N*64]
    float* ls  = out + E + (size_t)N * 64;   // [N*64]
    float* M   = out + E;                    // mu|ls region doubles as N*128 fp32 scratch

    // region X (ws[0..NB)):   hpA (fp16, mm1/mm3 out) / R1 (fp32, agg MODE0 out)
    // region Y (ws[NB..2NB)): hpB (fp16, agg1 out) / R3 (fp32, mm2 out) / zh (fp16)
    float* ws = (float*)d_ws;
    float*  R1  = ws;
    __half* hpA = (__half*)ws;
    float*  R3  = ws + NB;
    __half* hpB = (__half*)(ws + NB);
    __half* zh  = (__half*)(ws + NB);
    float* c0 = ws + 2 * NB;
    const size_t P = 50176;   // >= N+1
    float* dis         = c0;
    int*   cnt         = (int*)(c0 + P);
    int*   row_ptr     = (int*)(c0 + 2 * P);
    int*   woff        = (int*)(c0 + 3 * P);
    int*   bsum        = (int*)(c0 + 4 * P);
    int*   src_sorted  = (int*)(c0 + 4 * P + 256);

    const int nscan = (N + 1023) / 1024;

    // ---- CSR build ----
    zero_int_k<<<(N + 255) / 256, 256, 0, stream>>>(cnt, N);
    count_dst_k<<<(E + 255) / 256, 256, 0, stream>>>(ei, cnt, E);
    compute_dis_k<<<(N + 255) / 256, 256, 0, stream>>>(cnt, dis, N);
    scan1_k<<<nscan, 1024, 0, stream>>>(cnt, row_ptr, bsum, N);
    scan2_k<<<1, 64, 0, stream>>>(bsum, nscan);
    scan3_k<<<nscan, 1024, 0, stream>>>(cnt, row_ptr, bsum, woff, N);
    scatter_edges_k<<<(E + 255) / 256, 256, 0, stream>>>(ei, woff, src_sorted, E);

    const int aggBlocks = (int)(((size_t)N * 64 + 255) / 256);
    dim3 g64((N + 63) / 64, 2), g32((N + 31) / 32, 2);

    // layer 1: G1' = dis*(x@W1) (fp16 hpA);  h1' = dis*relu(dis*S1 + b) -> hpB
    matmul2_k<128, 64, 0, 1><<<g64, 256, 0, stream>>>(x, x, 128, 0, 0, w_mu1, w_ls1,
                                                      nullptr, nullptr, nullptr, nullptr,
                                                      hpA, dis, 128, 0, 64, N);
    agg2h_k<1><<<aggBlocks, 256, 0, stream>>>(hpA, dis, row_ptr, src_sorted,
                                              b_mu1, b_ls1, nullptr, hpB, nullptr,
                                              nullptr, nullptr, nullptr, N);

    // layer 2 (reordered): a2 = dis*S2 -> R1 (fp32);  h2 = relu(a2@W2 + b2) -> M / R3
    agg2h_k<0><<<aggBlocks, 256, 0, stream>>>(hpB, dis, row_ptr, src_sorted,
                                              nullptr, nullptr, nullptr, nullptr, R1,
                                              nullptr, nullptr, nullptr, N);
    matmul2_k<64, 128, 1, 0><<<g32, 256, 0, stream>>>(R1, R1, 128, 0, 64, w_mu2, w_ls2,
                                                      b_mu2, b_ls2, M, R3, nullptr, nullptr,
                                                      128, 0, 0, N);

    // layer 3: G3' = dis*(h2@W3) (fp16 hpA);  final agg -> mu, ls, zh
    matmul2_k<128, 64, 0, 1><<<g64, 256, 0, stream>>>(M, R3, 128, 0, 0, w_mu3, w_ls3,
                                                      nullptr, nullptr, nullptr, nullptr,
                                                      hpA, dis, 128, 0, 64, N);
    agg2h_k<2><<<aggBlocks, 256, 0, stream>>>(hpA, dis, row_ptr, src_sorted,
                                              b_mu3, b_ls3, eps, nullptr, nullptr,
                                              mu, ls, zh, N);

    // decode (fp16 z rows)
    decoder_k<<<(int)(((size_t)E * 16 + 255) / 256), 256, 0, stream>>>(ei, zh, adj, E);
}

// Round 10
// 271.959 us; speedup vs baseline: 3.4067x; 1.0435x over previous
//
#include <hip/hip_runtime.h>
#include <hip/hip_bf16.h>
#include <hip/hip_fp16.h>
#include <math.h>

// ---------------------------------------------------------------------------
// GRAPH_VAE_V3: GCN-VAE encoder + inner-product decoder.
// R10: packed-fp16 accumulation in aggs (v_pk_add_f16, 4x fewer VALU ops),
// full fp16 inter-kernel pipeline (a2/h2 fp16, matmul fp16-A staging),
// 16-edge gather unroll.  Epilogues in fp32.
// ---------------------------------------------------------------------------

__global__ void zero_int_k(int* __restrict__ p, int n) {
    int i = blockIdx.x * blockDim.x + threadIdx.x;
    if (i < n) p[i] = 0;
}

__global__ void count_dst_k(const int* __restrict__ ei, int* __restrict__ cnt, int E) {
    int e = blockIdx.x * blockDim.x + threadIdx.x;
    if (e < E) atomicAdd(&cnt[ei[E + e]], 1);
}

__global__ void compute_dis_k(const int* __restrict__ cnt, float* __restrict__ dis, int n) {
    int i = blockIdx.x * blockDim.x + threadIdx.x;
    if (i < n) dis[i] = rsqrtf((float)cnt[i] + 1.0f);
}

// ---- 3-phase parallel scan ----
__global__ void scan1_k(const int* __restrict__ cnt, int* __restrict__ row_ptr,
                        int* __restrict__ bsum, int n) {
    __shared__ int wsum[16];
    int tid = threadIdx.x, lane = tid & 63, wv = tid >> 6;
    int i = blockIdx.x * 1024 + tid;
    int v = (i < n) ? cnt[i] : 0;
    int x = v;
#pragma unroll
    for (int off = 1; off < 64; off <<= 1) {
        int t = __shfl_up(x, off, 64);
        if (lane >= off) x += t;
    }
    if (lane == 63) wsum[wv] = x;
    __syncthreads();
    if (wv == 0 && lane < 16) {
        int y = wsum[lane];
#pragma unroll
        for (int off = 1; off < 16; off <<= 1) {
            int t = __shfl_up(y, off, 64);
            if (lane >= off) y += t;
        }
        wsum[lane] = y;
    }
    __syncthreads();
    int incl = x + ((wv == 0) ? 0 : wsum[wv - 1]);
    if (i < n) row_ptr[i + 1] = incl;
    if (tid == 1023) bsum[blockIdx.x] = incl;
}

__global__ void scan2_k(int* __restrict__ bsum, int nb) {
    int lane = threadIdx.x;
    int v = (lane < nb) ? bsum[lane] : 0;
    int x = v;
#pragma unroll
    for (int off = 1; off < 64; off <<= 1) {
        int t = __shfl_up(x, off, 64);
        if (lane >= off) x += t;
    }
    if (lane < nb) bsum[lane] = x - v;
}

__global__ void scan3_k(const int* __restrict__ cnt, int* __restrict__ row_ptr,
                        const int* __restrict__ bsum, int* __restrict__ woff, int n) {
    int i = blockIdx.x * 1024 + threadIdx.x;
    if (i == 0) row_ptr[0] = 0;
    if (i < n) {
        int r = row_ptr[i + 1] + bsum[blockIdx.x];
        row_ptr[i + 1] = r;
        woff[i] = r - cnt[i];
    }
}

// scatter: only the src index (4B/edge)
__global__ void scatter_edges_k(const int* __restrict__ ei, int* __restrict__ woff,
                                int* __restrict__ src_sorted, int E) {
    int e = blockIdx.x * blockDim.x + threadIdx.x;
    if (e < E) {
        int s = ei[e];
        int d = ei[E + e];
        int pos = atomicAdd(&woff[d], 1);
        src_sorted[pos] = s;
    }
}

// Branch-pair matmul, K-chunked A staging (KC=32), fp16 output.
// AH=1: A is fp16 (converted to fp32 during LDS staging).
// EPI=1: bias+relu.  PRE=1: multiply by dis[r] before fp16 store.
template <int K, int OUT, int EPI, int PRE, int AH>
__global__ __launch_bounds__(256, 4) void matmul2_k(
        const void* __restrict__ AAv, const void* __restrict__ ABv, int lda,
        int offaA, int offaB,
        const float* __restrict__ WA, const float* __restrict__ WB,
        const float* __restrict__ bA, const float* __restrict__ bB,
        __half* __restrict__ HHA, __half* __restrict__ HHB,
        const float* __restrict__ dis,
        int ldh, int offhA, int offhB, int n) {
    constexpr int TX = OUT / 4;
    constexpr int TY = 256 / TX;
    constexpr int TM = TY * 4;
    constexpr int KC = 32, KC4 = 8, KC8 = 4;
    __shared__ float w_lds[K * OUT];
    __shared__ float a_lds[TM * KC];

    int by = blockIdx.y;
    const float*  Af = (const float*)(by ? ABv : AAv);
    const __half* Ah = (const __half*)(by ? ABv : AAv);
    const float* W  = by ? WB : WA;
    const float* bi = by ? bB : bA;
    __half*      HH = by ? HHB : HHA;
    int offa = by ? offaB : offaA;
    int offh = by ? offhB : offhA;

    int tid = threadIdx.x;
    for (int idx = tid; idx < K * OUT / 4; idx += 256)
        ((float4*)w_lds)[idx] = ((const float4*)W)[idx];

    int row0 = blockIdx.x * TM;
    int tx = tid % TX;
    int ty = tid / TX;

    float4 acc[4];
#pragma unroll
    for (int i = 0; i < 4; ++i) acc[i] = make_float4(0.f, 0.f, 0.f, 0.f);

    int abase[4], akey[4];
#pragma unroll
    for (int i = 0; i < 4; ++i) {
        int r = ty * 4 + i;
        abase[i] = r * KC;
        akey[i]  = (r >> 2) & 7;
    }

    for (int kc = 0; kc < K; kc += KC) {
        __syncthreads();
        if constexpr (AH) {
            for (int f8 = tid; f8 < TM * KC8; f8 += 256) {
                int row  = f8 / KC8;
                int col8 = f8 % KC8;
                float f[8] = {0.f, 0.f, 0.f, 0.f, 0.f, 0.f, 0.f, 0.f};
                if (row0 + row < n) {
                    uint4 u = *(const uint4*)&Ah[(size_t)(row0 + row) * lda + offa + kc + col8 * 8];
                    const __half2* p = (const __half2*)&u;
#pragma unroll
                    for (int i = 0; i < 4; ++i) {
                        float2 t = __half22float2(p[i]);
                        f[2 * i] = t.x; f[2 * i + 1] = t.y;
                    }
                }
                int key = (row >> 2) & 7;
                *(float4*)&a_lds[row * KC + (((2 * col8) ^ key) << 2)] =
                    make_float4(f[0], f[1], f[2], f[3]);
                *(float4*)&a_lds[row * KC + (((2 * col8 + 1) ^ key) << 2)] =
                    make_float4(f[4], f[5], f[6], f[7]);
            }
        } else {
            for (int f4 = tid; f4 < TM * KC4; f4 += 256) {
                int row  = f4 >> 3;
                int col4 = f4 & 7;
                float4 v = make_float4(0.f, 0.f, 0.f, 0.f);
                if (row0 + row < n)
                    v = *(const float4*)&Af[(size_t)(row0 + row) * lda + offa + kc + (col4 << 2)];
                *(float4*)&a_lds[row * KC + ((col4 ^ ((row >> 2) & 7)) << 2)] = v;
            }
        }
        __syncthreads();

#pragma unroll
        for (int k = 0; k < KC; k += 4) {
            int k4 = k >> 2;
            float af[4][4];
#pragma unroll
            for (int i = 0; i < 4; ++i) {
                float4 a = *(const float4*)&a_lds[abase[i] + ((k4 ^ akey[i]) << 2)];
                af[i][0] = a.x; af[i][1] = a.y; af[i][2] = a.z; af[i][3] = a.w;
            }
#pragma unroll
            for (int j = 0; j < 4; ++j) {
                float4 wv = ((const float4*)w_lds)[(kc + k + j) * TX + tx];
#pragma unroll
                for (int i = 0; i < 4; ++i) {
                    acc[i].x += af[i][j] * wv.x;
                    acc[i].y += af[i][j] * wv.y;
                    acc[i].z += af[i][j] * wv.z;
                    acc[i].w += af[i][j] * wv.w;
                }
            }
        }
    }

#pragma unroll
    for (int i = 0; i < 4; ++i) {
        int r = row0 + ty * 4 + i;
        if (r < n) {
            float4 o = acc[i];
            if (EPI == 1) {
                float4 b = ((const float4*)bi)[tx];
                o.x = fmaxf(o.x + b.x, 0.f);
                o.y = fmaxf(o.y + b.y, 0.f);
                o.z = fmaxf(o.z + b.z, 0.f);
                o.w = fmaxf(o.w + b.w, 0.f);
            }
            float dsc = (PRE == 1) ? dis[r] : 1.f;
            __half2 h0 = __floats2half2_rn(o.x * dsc, o.y * dsc);
            __half2 h1 = __floats2half2_rn(o.z * dsc, o.w * dsc);
            uint2 u = make_uint2(*(unsigned*)&h0, *(unsigned*)&h1);
            *(uint2*)&HH[(size_t)r * ldh + offh + tx * 4] = u;
        }
    }
}

// Dual-branch CSR aggregation over dis-prescaled fp16 rows [mu64|ls64] (256B).
// Packed fp16 accumulate (v_pk_add_f16), fp32 epilogue.
// Wave: 4 edge-groups (g) x 16 channel-octets (q);  S_d = sum G'_s + G'_d.
// MODE 0: fp16(dis*S) -> oH      MODE 1: fp16(dis*relu(dis*S+b)) -> oH
// MODE 2: mu=relu(dis*S+b), ls=clamp, z=mu+eps*exp(ls) -> oM,oL (fp32) + zh (fp16)
template <int MODE>
__global__ void agg2h_k(const __half* __restrict__ h, const float* __restrict__ dis,
                        const int* __restrict__ row_ptr, const int* __restrict__ srcs,
                        const float* __restrict__ bM, const float* __restrict__ bL,
                        const float* __restrict__ eps,
                        __half* __restrict__ oH,
                        float* __restrict__ oM, float* __restrict__ oL,
                        __half* __restrict__ zh, int n) {
    int wid  = (int)((blockIdx.x * (size_t)blockDim.x + threadIdx.x) >> 6);
    int lane = threadIdx.x & 63;
    if (wid >= n) return;
    int g = lane >> 4;   // edge sub-group
    int q = lane & 15;   // channel octet
    const __half* hq = h + 8 * q;

    __half2 acc2[4];
    if (g == 0) {  // self-loop term
        uint4 r = *(const uint4*)&hq[(size_t)wid << 7];
        const __half2* hp = (const __half2*)&r;
#pragma unroll
        for (int i = 0; i < 4; ++i) acc2[i] = hp[i];
    } else {
        __half2 z2 = __float2half2_rn(0.f);
#pragma unroll
        for (int i = 0; i < 4; ++i) acc2[i] = z2;
    }

    int beg = row_ptr[wid], end = row_ptr[wid + 1];
    for (int cb = beg; cb < end; cb += 64) {
        int m = end - cb;
        if (m > 64) m = 64;
        int sv = 0;
        if (lane < m) sv = srcs[cb + lane];
        int j = 0;
        for (; j + 16 <= m; j += 16) {
            int s0 = __shfl(sv, j + g, 64);
            int s1 = __shfl(sv, j + 4 + g, 64);
            int s2 = __shfl(sv, j + 8 + g, 64);
            int s3 = __shfl(sv, j + 12 + g, 64);
            uint4 r0 = *(const uint4*)&hq[(size_t)s0 << 7];
            uint4 r1 = *(const uint4*)&hq[(size_t)s1 << 7];
            uint4 r2 = *(const uint4*)&hq[(size_t)s2 << 7];
            uint4 r3 = *(const uint4*)&hq[(size_t)s3 << 7];
            const __half2* p0 = (const __half2*)&r0;
            const __half2* p1 = (const __half2*)&r1;
            const __half2* p2 = (const __half2*)&r2;
            const __half2* p3 = (const __half2*)&r3;
#pragma unroll
            for (int i = 0; i < 4; ++i)
                acc2[i] = __hadd2(acc2[i],
                          __hadd2(__hadd2(p0[i], p1[i]), __hadd2(p2[i], p3[i])));
        }
        for (; j + 8 <= m; j += 8) {
            int s0 = __shfl(sv, j + g, 64);
            int s1 = __shfl(sv, j + 4 + g, 64);
            uint4 r0 = *(const uint4*)&hq[(size_t)s0 << 7];
            uint4 r1 = *(const uint4*)&hq[(size_t)s1 << 7];
            const __half2* p0 = (const __half2*)&r0;
            const __half2* p1 = (const __half2*)&r1;
#pragma unroll
            for (int i = 0; i < 4; ++i)
                acc2[i] = __hadd2(acc2[i], __hadd2(p0[i], p1[i]));
        }
        for (; j < m; j += 4) {
            int idx = j + g;
            int s0 = __shfl(sv, (idx < m) ? idx : j, 64);
            if (idx < m) {
                uint4 r0 = *(const uint4*)&hq[(size_t)s0 << 7];
                const __half2* p0 = (const __half2*)&r0;
#pragma unroll
                for (int i = 0; i < 4; ++i) acc2[i] = __hadd2(acc2[i], p0[i]);
            }
        }
    }

    // combine the 4 edge-groups (still fp16)
#pragma unroll
    for (int i = 0; i < 4; ++i) {
        int u0 = *reinterpret_cast<int*>(&acc2[i]);
        int v0 = __shfl_xor(u0, 16, 64);
        acc2[i] = __hadd2(acc2[i], *reinterpret_cast<__half2*>(&v0));
        int u1 = *reinterpret_cast<int*>(&acc2[i]);
        int v1 = __shfl_xor(u1, 32, 64);
        acc2[i] = __hadd2(acc2[i], *reinterpret_cast<__half2*>(&v1));
    }

    // fp32 epilogue
    float di = dis[wid];
    float acc[8];
#pragma unroll
    for (int i = 0; i < 4; ++i) {
        float2 f = __half22float2(acc2[i]);
        acc[2 * i]     = f.x * di;
        acc[2 * i + 1] = f.y * di;
    }

    if (MODE == 0) {
        if (g == 0) {
            __half2 hh[4];
#pragma unroll
            for (int i = 0; i < 4; ++i) hh[i] = __floats2half2_rn(acc[2 * i], acc[2 * i + 1]);
            *(uint4*)&oH[(size_t)wid * 128 + 8 * q] = *(uint4*)hh;
        }
    } else if (MODE == 1) {
        if (g == 0) {
            const float* bs = (q < 8) ? bM + 8 * q : bL + 8 * q - 64;
            __half2 hh[4];
#pragma unroll
            for (int i = 0; i < 8; i += 2) {
                float a0 = fmaxf(acc[i] + bs[i], 0.f) * di;
                float a1 = fmaxf(acc[i + 1] + bs[i + 1], 0.f) * di;
                hh[i >> 1] = __floats2half2_rn(a0, a1);
            }
            *(uint4*)&oH[(size_t)wid * 128 + 8 * q] = *(uint4*)hh;
        }
    } else {
        const float* bs = (q < 8) ? bM + 8 * q : bL + 8 * q - 64;
        float act[8];
#pragma unroll
        for (int i = 0; i < 8; ++i) {
            float a = fmaxf(acc[i] + bs[i], 0.f);
            if (q >= 8) a = fminf(a, 10.f);
            act[i] = a;
        }
        float lsv[8];
#pragma unroll
        for (int i = 0; i < 8; ++i) lsv[i] = __shfl(act[i], lane + 8, 64);
        if (g == 0) {
            size_t ob = (size_t)wid * 64;
            if (q < 8) {
                *(float4*)&oM[ob + 8 * q]     = make_float4(act[0], act[1], act[2], act[3]);
                *(float4*)&oM[ob + 8 * q + 4] = make_float4(act[4], act[5], act[6], act[7]);
                float4 e0 = *(const float4*)&eps[ob + 8 * q];
                float4 e1 = *(const float4*)&eps[ob + 8 * q + 4];
                float zz[8];
                zz[0] = fmaf(e0.x, expf(lsv[0]), act[0]);
                zz[1] = fmaf(e0.y, expf(lsv[1]), act[1]);
                zz[2] = fmaf(e0.z, expf(lsv[2]), act[2]);
                zz[3] = fmaf(e0.w, expf(lsv[3]), act[3]);
                zz[4] = fmaf(e1.x, expf(lsv[4]), act[4]);
                zz[5] = fmaf(e1.y, expf(lsv[5]), act[5]);
                zz[6] = fmaf(e1.z, expf(lsv[6]), act[6]);
                zz[7] = fmaf(e1.w, expf(lsv[7]), act[7]);
                __half2 zh4[4];
#pragma unroll
                for (int i = 0; i < 4; ++i) zh4[i] = __floats2half2_rn(zz[2 * i], zz[2 * i + 1]);
                *(uint4*)&zh[ob + 8 * q] = *(uint4*)zh4;
            } else {
                int qq = q - 8;
                *(float4*)&oL[ob + 8 * qq]     = make_float4(act[0], act[1], act[2], act[3]);
                *(float4*)&oL[ob + 8 * qq + 4] = make_float4(act[4], act[5], act[6], act[7]);
            }
        }
    }
}

// adj[e] = sigmoid( dot(z[src], z[dst]) ): 16 lanes/edge, fp16 z rows (128B)
__global__ void decoder_k(const int* __restrict__ ei, const __half* __restrict__ zh,
                          float* __restrict__ adj, int E) {
    int t = blockIdx.x * 256 + threadIdx.x;
    int e = t >> 4;
    int q = threadIdx.x & 15;
    if (e >= E) return;
    int s = ei[e];
    int d = ei[E + e];
    const uint2* z2 = (const uint2*)zh;
    uint2 ua = z2[(size_t)s * 16 + q];
    uint2 ub = z2[(size_t)d * 16 + q];
    const __half2* pa = (const __half2*)&ua;
    const __half2* pb = (const __half2*)&ub;
    float p = 0.f;
#pragma unroll
    for (int i = 0; i < 2; ++i) {
        float2 fa = __half22float2(pa[i]);
        float2 fb = __half22float2(pb[i]);
        p = fmaf(fa.x, fb.x, p);
        p = fmaf(fa.y, fb.y, p);
    }
    p += __shfl_xor(p, 8);
    p += __shfl_xor(p, 4);
    p += __shfl_xor(p, 2);
    p += __shfl_xor(p, 1);
    if (q == 0) adj[e] = 1.f / (1.f + expf(-p));
}

extern "C" void kernel_launch(void* const* d_in, const int* in_sizes, int n_in,
                              void* d_out, int out_size, void* d_ws, size_t ws_size,
                              hipStream_t stream) {
    const float* x   = (const float*)d_in[0];
    const int*   ei  = (const int*)d_in[1];
    const float* eps = (const float*)d_in[2];
    const float* w_mu1 = (const float*)d_in[3];
    const float* b_mu1 = (const float*)d_in[4];
    const float* w_mu2 = (const float*)d_in[5];
    const float* b_mu2 = (const float*)d_in[6];
    const float* w_mu3 = (const float*)d_in[7];
    const float* b_mu3 = (const float*)d_in[8];
    const float* w_ls1 = (const float*)d_in[9];
    const float* b_ls1 = (const float*)d_in[10];
    const float* w_ls2 = (const float*)d_in[11];
    const float* b_ls2 = (const float*)d_in[12];
    const float* w_ls3 = (const float*)d_in[13];
    const float* b_ls3 = (const float*)d_in[14];

    const int N = in_sizes[0] / 128;
    const int E = in_sizes[1] / 2;
    const size_t NB = (size_t)N * 128;  // floats per region

    float* out = (float*)d_out;
    float* adj = out;                        // [E]
    float* mu  = out + E;                    // [N*64]
    float* ls  = out + E + (size_t)N * 64;   // [N*64]

    // region X (ws[0..NB)):   hpA (mm1/mm3 fp16 out)  |  a2h (MODE0 fp16 out)
    // region Y (ws[NB..2NB)): hpB (agg1 fp16 out)  |  h2mu+h2ls (mm2 fp16 out)  |  zh
    float* ws = (float*)d_ws;
    __half* hpA  = (__half*)ws;
    __half* a2h  = (__half*)ws;
    __half* hpB  = (__half*)(ws + NB);
    __half* h2mu = (__half*)(ws + NB);
    __half* h2ls = h2mu + (size_t)N * 128;
    __half* zh   = (__half*)(ws + NB);
    float* c0 = ws + 2 * NB;
    const size_t P = 50176;   // >= N+1
    float* dis         = c0;
    int*   cnt         = (int*)(c0 + P);
    int*   row_ptr     = (int*)(c0 + 2 * P);
    int*   woff        = (int*)(c0 + 3 * P);
    int*   bsum        = (int*)(c0 + 4 * P);
    int*   src_sorted  = (int*)(c0 + 4 * P + 256);

    const int nscan = (N + 1023) / 1024;

    // ---- CSR build ----
    zero_int_k<<<(N + 255) / 256, 256, 0, stream>>>(cnt, N);
    count_dst_k<<<(E + 255) / 256, 256, 0, stream>>>(ei, cnt, E);
    compute_dis_k<<<(N + 255) / 256, 256, 0, stream>>>(cnt, dis, N);
    scan1_k<<<nscan, 1024, 0, stream>>>(cnt, row_ptr, bsum, N);
    scan2_k<<<1, 64, 0, stream>>>(bsum, nscan);
    scan3_k<<<nscan, 1024, 0, stream>>>(cnt, row_ptr, bsum, woff, N);
    scatter_edges_k<<<(E + 255) / 256, 256, 0, stream>>>(ei, woff, src_sorted, E);

    const int aggBlocks = (int)(((size_t)N * 64 + 255) / 256);
    dim3 g64((N + 63) / 64, 2), g32((N + 31) / 32, 2);

    // layer 1: G1' = dis*(x@W1) -> hpA;  h1' = dis*relu(dis*S1+b) -> hpB
    matmul2_k<128, 64, 0, 1, 0><<<g64, 256, 0, stream>>>(
        x, x, 128, 0, 0, w_mu1, w_ls1, nullptr, nullptr, hpA, hpA, dis, 128, 0, 64, N);
    agg2h_k<1><<<aggBlocks, 256, 0, stream>>>(hpA, dis, row_ptr, src_sorted,
                                              b_mu1, b_ls1, nullptr, hpB,
                                              nullptr, nullptr, nullptr, N);

    // layer 2 (reordered): a2 = dis*S2 -> a2h (fp16);  h2 = relu(a2@W2+b2) -> h2mu/h2ls (fp16)
    agg2h_k<0><<<aggBlocks, 256, 0, stream>>>(hpB, dis, row_ptr, src_sorted,
                                              nullptr, nullptr, nullptr, a2h,
                                              nullptr, nullptr, nullptr, N);
    matmul2_k<64, 128, 1, 0, 1><<<g32, 256, 0, stream>>>(
        a2h, a2h, 128, 0, 64, w_mu2, w_ls2, b_mu2, b_ls2, h2mu, h2ls, dis, 128, 0, 0, N);

    // layer 3: G3' = dis*(h2@W3) -> hpA;  final agg -> mu, ls, zh
    matmul2_k<128, 64, 0, 1, 1><<<g64, 256, 0, stream>>>(
        h2mu, h2ls, 128, 0, 0, w_mu3, w_ls3, nullptr, nullptr, hpA, hpA, dis, 128, 0, 64, N);
    agg2h_k<2><<<aggBlocks, 256, 0, stream>>>(hpA, dis, row_ptr, src_sorted,
                                              b_mu3, b_ls3, eps, nullptr,
                                              mu, ls, zh, N);

    // decode (fp16 z rows)
    decoder_k<<<(int)(((size_t)E * 16 + 255) / 256), 256, 0, stream>>>(ei, zh, adj, E);
}